// Round 3
// baseline (390.779 us; speedup 1.0000x reference)
//
#include <hip/hip_runtime.h>
#include <hip/hip_bf16.h>
#include <math.h>

#define BB 4
#define LL 512
#define EMB 256
#define NH 8
#define HD 32
#define NB_ 3
#define CCN 10
#define NBKT 32
#define SCALE 0.17677669529663687f
#define SCP 520   // score row pitch

typedef __hip_bfloat16 bf16;

// Flag-adaptive global load: isf=1 -> fp32 data, isf=0 -> bf16 data.
__device__ __forceinline__ float ldf(const void* p, long idx, int isf) {
    if (isf) return ((const float*)p)[idx];
    unsigned short raw = ((const unsigned short*)p)[idx];
    return __uint_as_float(((unsigned int)raw) << 16);
}
__device__ __forceinline__ int bm_of(int tq, int tk) {
    return (tq * tk != 0) ? ((tq - 1) * 3 + tk) : 0;
}

// ---------------- Kf: dtype probe ----------------
// Even-indexed ushorts of Wq interpreted as bf16: genuine bf16 weights are
// ~0.02*N(0,1) (always in [1e-8,1e2]); fp32 low-mantissa halves are log-uniform
// garbage (~13% in range). Threshold at 50%.
__global__ void k_flag(const void* __restrict__ wq, int* __restrict__ flag) {
    __shared__ int cnt;
    if (threadIdx.x == 0) cnt = 0;
    __syncthreads();
    const unsigned short* u = (const unsigned short*)wq;
    unsigned short raw = u[threadIdx.x * 2];
    float v = __uint_as_float(((unsigned int)raw) << 16);
    float a = fabsf(v);
    int good = (a > 1e-8f && a < 1e2f) ? 1 : 0;
    atomicAdd(&cnt, good);
    __syncthreads();
    if (threadIdx.x == 0) flag[0] = (cnt > 256) ? 0 : 1;   // 0 = bf16, 1 = fp32
}

// ---------------- K0: W1_/W2_ (alpha-softmax combine) + bucket table ----------------
__global__ void k_prep(const void* __restrict__ alpha1, const void* __restrict__ W1,
                       const void* __restrict__ alpha2, const void* __restrict__ W2,
                       float* __restrict__ W1s, float* __restrict__ W2s, int* __restrict__ tbl,
                       const int* __restrict__ fl) {
    int isf = *fl;
    int blk = blockIdx.x, tid = threadIdx.x;
    if (blk < 160) {
        const void* alpha = (blk < 80) ? alpha1 : alpha2;
        const void* W     = (blk < 80) ? W1 : W2;
        float* Ws         = (blk < 80) ? W1s : W2s;
        int idx = blk % 80;
        int cc = idx / NH, h = idx % NH;
        float a0 = ldf(alpha, cc * NB_ * NH + 0 * NH + h, isf);
        float a1 = ldf(alpha, cc * NB_ * NH + 1 * NH + h, isf);
        float a2 = ldf(alpha, cc * NB_ * NH + 2 * NH + h, isf);
        float mx = fmaxf(a0, fmaxf(a1, a2));
        float e0 = __expf(a0 - mx), e1 = __expf(a1 - mx), e2 = __expf(a2 - mx);
        float inv = 1.0f / (e0 + e1 + e2);
        e0 *= inv; e1 *= inv; e2 *= inv;
        for (int i = tid; i < HD * HD; i += blockDim.x) {
            int m = i >> 5, n = i & 31;
            float acc = e0 * ldf(W, ((0 * NH + h) * HD + m) * HD + n, isf)
                      + e1 * ldf(W, ((1 * NH + h) * HD + m) * HD + n, isf)
                      + e2 * ldf(W, ((2 * NH + h) * HD + m) * HD + n, isf);
            Ws[((cc * NH + h) * HD + m) * HD + n] = acc;
        }
    } else {
        for (int d = tid; d < LL; d += blockDim.x) {
            int v;
            if (d < 8) v = d;
            else {
                double r = log((double)d / 8.0) / log(5.0);
                v = 8 + (int)(r * 8.0);
                if (v > 15) v = 15;
            }
            tbl[d] = v;
        }
    }
}

// ---------------- Kp: stable counting sort of tokens by type (per batch) ----------------
__global__ void k_perm(const int* __restrict__ ts, int* __restrict__ perm, int* __restrict__ ptype) {
    __shared__ int4 sc[LL];
    int b = blockIdx.x, t = threadIdx.x;  // 512 threads
    int ty = ts[b * LL + t];
    int4 f; f.x = (ty == 0); f.y = (ty == 1); f.z = (ty == 2); f.w = (ty == 3);
    sc[t] = f;
    __syncthreads();
    for (int off = 1; off < LL; off <<= 1) {
        int4 add; bool has = (t >= off);
        if (has) add = sc[t - off];
        __syncthreads();
        if (has) { sc[t].x += add.x; sc[t].y += add.y; sc[t].z += add.z; sc[t].w += add.w; }
        __syncthreads();
    }
    int4 tot = sc[LL - 1];
    int4 incl = sc[t];
    int base, rank;
    if (ty == 0)      { base = 0;                         rank = incl.x - 1; }
    else if (ty == 1) { base = tot.x;                     rank = incl.y - 1; }
    else if (ty == 2) { base = tot.x + tot.y;             rank = incl.z - 1; }
    else              { base = tot.x + tot.y + tot.z;     rank = incl.w - 1; }
    int pos = base + rank;
    perm[b * LL + pos] = t;
    ptype[b * LL + pos] = ty;
}

// ---------------- K1: QKV projection, tokens processed in sorted order ----------------
__global__ void k_qkv(const void* __restrict__ x, const int* __restrict__ perm, const int* __restrict__ ptype,
                      const void* __restrict__ Wq, const void* __restrict__ Wk, const void* __restrict__ Wv,
                      float* __restrict__ qp, float* __restrict__ kp, float* __restrict__ vp,
                      const int* __restrict__ fl) {
    __shared__ float xs[8][EMB];
    __shared__ int tok[8];
    __shared__ int tloc[8];
    int isf = *fl;
    int g = blockIdx.x;
    int which = g / (BB * 64);
    int rem = g % (BB * 64);
    int b = rem / 64, i8 = rem % 64, i0 = i8 * 8;
    int tid = threadIdx.x;
    if (tid < 8) {
        tok[tid]  = perm[b * LL + i0 + tid];
        tloc[tid] = ptype[b * LL + i0 + tid];
    }
    __syncthreads();
    for (int i = tid; i < 8 * EMB; i += 256) {
        int tt = i >> 8, e = i & 255;
        xs[tt][e] = ldf(x, (long)(b * LL + tok[tt]) * EMB + e, isf);
    }
    __syncthreads();
    const void* W = (which == 0) ? Wq : (which == 1 ? Wk : Wv);
    float* outp   = (which == 0) ? qp : (which == 1 ? kp : vp);
    int j = tid;
    float acc[8];
#pragma unroll
    for (int tt = 0; tt < 8; tt++) acc[tt] = 0.f;
    int c0 = tloc[0];
    bool uni = true;
#pragma unroll
    for (int tt = 1; tt < 8; tt++) uni = uni && (tloc[tt] == c0);
    if (uni) {
        long wb = (long)c0 * EMB * EMB + j;
        for (int e0 = 0; e0 < EMB; e0 += 4) {
            float w0 = ldf(W, wb + (long)(e0 + 0) * EMB, isf);
            float w1 = ldf(W, wb + (long)(e0 + 1) * EMB, isf);
            float w2 = ldf(W, wb + (long)(e0 + 2) * EMB, isf);
            float w3 = ldf(W, wb + (long)(e0 + 3) * EMB, isf);
#pragma unroll
            for (int tt = 0; tt < 8; tt++) {
                float4 xv = *(const float4*)&xs[tt][e0];
                acc[tt] += xv.x * w0 + xv.y * w1 + xv.z * w2 + xv.w * w3;
            }
        }
    } else {  // rare: type-boundary block
        for (int tt = 0; tt < 8; tt++) {
            long wb = (long)tloc[tt] * EMB * EMB + j;
            float a = 0.f;
            for (int e = 0; e < EMB; e++) a += xs[tt][e] * ldf(W, wb + (long)e * EMB, isf);
            acc[tt] = a;
        }
    }
    int h = j >> 5, d = j & 31;
#pragma unroll
    for (int tt = 0; tt < 8; tt++)
        outp[((b * NH + h) * LL + i0 + tt) * HD + d] = acc[tt];
}

// ---------------- K2: attention core: qt -> scores -> softmax -> typed-bucket PV -> ctx ----------------
// grid: BB*NH*32 blocks (16 queries each), 256 threads. Static LDS = 65,472 B (<= 64 KiB).
__global__ __launch_bounds__(256, 2) void k_attn(
    const float* __restrict__ qp, const float* __restrict__ kp, const float* __restrict__ vp,
    const int* __restrict__ perm, const int* __restrict__ ptype, const int* __restrict__ tbl,
    const void* __restrict__ rp, const void* __restrict__ am,
    const float* __restrict__ W1s, const float* __restrict__ W2s,
    float* __restrict__ ctx, const int* __restrict__ fl) {
    __shared__ float sc[16 * SCP];       // 33280 B
    __shared__ float kbuf[64 * 36];      // 9216 B (reused as sb[16][132] later)
    __shared__ float vbuf[64 * 32];      // 8192 B (reused as q staging in prologue)
    __shared__ float qt_l[16 * 4 * 36];  // 9216 B
    __shared__ float rp_l[CCN * NBKT];   // 1280 B
    __shared__ int ktp_l[LL];            // 2048 B
    __shared__ int kor_l[LL];            // 2048 B
    __shared__ int qor_l[16];
    __shared__ int qty_l[16];
    __shared__ float inv_l[16];

    int isf = *fl;
    int blk = blockIdx.x;
    int b = blk >> 8, h = (blk >> 5) & 7, q16 = blk & 31;
    int i0q = q16 * 16;
    int tid = threadIdx.x;

    for (int i = tid; i < CCN * NBKT; i += 256) rp_l[i] = ldf(rp, (long)i * NH + h, isf);
    for (int i = tid; i < LL; i += 256) { kor_l[i] = perm[b * LL + i]; ktp_l[i] = ptype[b * LL + i]; }
    if (tid < 16) { qor_l[tid] = perm[b * LL + i0q + tid]; qty_l[tid] = ptype[b * LL + i0q + tid]; }
    // stage 16 q-rows into vbuf (free until pass 3)
    for (int i = tid; i < 16 * 32; i += 256) {
        int q = i >> 5, m = i & 31;
        vbuf[q * 32 + m] = qp[((b * NH + h) * LL + i0q + q) * HD + m];
    }
    __syncthreads();

    // ---- fused qt: qt[q][tk][n] = sum_m q[m] * W1_[bm(tq,tk)][h][m][n] ----
    for (int i = tid; i < 16 * 128; i += 256) {
        int q = i >> 7, r = i & 127, tk = r >> 5, n = r & 31;
        int bmv = bm_of(qty_l[q], tk);
        const float* wb = &W1s[((bmv * NH + h) * HD) * HD + n];
        const float* qr = &vbuf[q * 32];
        float acc = 0.f;
#pragma unroll
        for (int m = 0; m < HD; m++) acc += qr[m] * wb[m * HD];
        qt_l[(q * 4 + tk) * 36 + n] = acc;
    }
    __syncthreads();

    // ---- pass 1: scores ----
    int k = tid & 63, qg = tid >> 6;
    for (int kt0 = 0; kt0 < LL; kt0 += 64) {
        for (int i = tid; i < 64 * 32; i += 256) {
            int kk = i >> 5, m = i & 31;
            kbuf[kk * 36 + m] = kp[((b * NH + h) * LL + kt0 + kk) * HD + m];
        }
        __syncthreads();
        int kpi = kt0 + k;
        int ko = kor_l[kpi];
        int tk = ktp_l[kpi];
        float4 kr[8];
#pragma unroll
        for (int mm = 0; mm < 8; mm++) kr[mm] = *(const float4*)&kbuf[k * 36 + mm * 4];
#pragma unroll
        for (int i = 0; i < 4; i++) {
            int q = qg * 4 + i;
            int tq = qty_l[q];
            int bmv = bm_of(tq, tk);
            const float* qrow = &qt_l[(q * 4 + tk) * 36];
            float s = 0.f;
#pragma unroll
            for (int mm = 0; mm < 8; mm++) {
                float4 qv = *(const float4*)&qrow[mm * 4];
                s += qv.x * kr[mm].x + qv.y * kr[mm].y + qv.z * kr[mm].z + qv.w * kr[mm].w;
            }
            int qo = qor_l[q];
            int dd = qo - ko;
            int ad = dd < 0 ? -dd : dd;
            int bk = (dd < 0 ? 16 : 0) + tbl[ad];
            float bias = rp_l[bmv * NBKT + bk];
            float mval = ldf(am, ((long)(b * LL + qo)) * LL + ko, isf);
            sc[q * SCP + kpi] = s * SCALE + bias + mval;
        }
        __syncthreads();
    }

    // ---- pass 2: softmax over 512 keys per query (16 threads / query) ----
    {
        int gq = tid >> 4, t16 = tid & 15;
        float mx = -1e30f;
        for (int j = 0; j < 32; j++) mx = fmaxf(mx, sc[gq * SCP + t16 + 16 * j]);
#pragma unroll
        for (int off = 1; off < 16; off <<= 1) mx = fmaxf(mx, __shfl_xor(mx, off, 16));
        float sum = 0.f;
        for (int j = 0; j < 32; j++) {
            int idx = gq * SCP + t16 + 16 * j;
            float e = __expf(sc[idx] - mx);
            sc[idx] = e; sum += e;
        }
#pragma unroll
        for (int off = 1; off < 16; off <<= 1) sum += __shfl_xor(sum, off, 16);
        if (t16 == 0) inv_l[gq] = 1.0f / sum;
    }
    __syncthreads();

    // ---- pass 3: typed-bucket accumulation s[tk][n] = sum_k e_k * v[k][n] ----
    int n4 = tid & 7, q = (tid >> 3) & 15, khalf = tid >> 7;
    float4 a0 = make_float4(0, 0, 0, 0), a1 = a0, a2 = a0, a3 = a0;
    for (int kt0 = 0; kt0 < LL; kt0 += 64) {
        for (int i = tid; i < 64 * 32; i += 256) {
            int kk = i >> 5, m = i & 31;
            vbuf[kk * 32 + m] = vp[((b * NH + h) * LL + kt0 + kk) * HD + m];
        }
        __syncthreads();
        for (int kk2 = 0; kk2 < 32; kk2++) {
            int kk = khalf * 32 + kk2;
            int kpi = kt0 + kk;
            int tk = ktp_l[kpi];  // wave-uniform (kpi uniform per wave)
            float p = sc[q * SCP + kpi];
            float4 v4 = *(const float4*)&vbuf[kk * 32 + n4 * 4];
            switch (tk) {
                case 0: a0.x += p * v4.x; a0.y += p * v4.y; a0.z += p * v4.z; a0.w += p * v4.w; break;
                case 1: a1.x += p * v4.x; a1.y += p * v4.y; a1.z += p * v4.z; a1.w += p * v4.w; break;
                case 2: a2.x += p * v4.x; a2.y += p * v4.y; a2.z += p * v4.z; a2.w += p * v4.w; break;
                default: a3.x += p * v4.x; a3.y += p * v4.y; a3.z += p * v4.z; a3.w += p * v4.w; break;
            }
        }
        __syncthreads();
    }
    float il = inv_l[q];
    float* sb = kbuf;  // reuse (kbuf idle after pass 1)
    if (khalf == 0) {
        sb[q * 132 + 0 * 32 + n4 * 4 + 0] = a0.x * il; sb[q * 132 + 0 * 32 + n4 * 4 + 1] = a0.y * il;
        sb[q * 132 + 0 * 32 + n4 * 4 + 2] = a0.z * il; sb[q * 132 + 0 * 32 + n4 * 4 + 3] = a0.w * il;
        sb[q * 132 + 1 * 32 + n4 * 4 + 0] = a1.x * il; sb[q * 132 + 1 * 32 + n4 * 4 + 1] = a1.y * il;
        sb[q * 132 + 1 * 32 + n4 * 4 + 2] = a1.z * il; sb[q * 132 + 1 * 32 + n4 * 4 + 3] = a1.w * il;
        sb[q * 132 + 2 * 32 + n4 * 4 + 0] = a2.x * il; sb[q * 132 + 2 * 32 + n4 * 4 + 1] = a2.y * il;
        sb[q * 132 + 2 * 32 + n4 * 4 + 2] = a2.z * il; sb[q * 132 + 2 * 32 + n4 * 4 + 3] = a2.w * il;
        sb[q * 132 + 3 * 32 + n4 * 4 + 0] = a3.x * il; sb[q * 132 + 3 * 32 + n4 * 4 + 1] = a3.y * il;
        sb[q * 132 + 3 * 32 + n4 * 4 + 2] = a3.z * il; sb[q * 132 + 3 * 32 + n4 * 4 + 3] = a3.w * il;
    }
    __syncthreads();
    if (khalf == 1) {
        sb[q * 132 + 0 * 32 + n4 * 4 + 0] += a0.x * il; sb[q * 132 + 0 * 32 + n4 * 4 + 1] += a0.y * il;
        sb[q * 132 + 0 * 32 + n4 * 4 + 2] += a0.z * il; sb[q * 132 + 0 * 32 + n4 * 4 + 3] += a0.w * il;
        sb[q * 132 + 1 * 32 + n4 * 4 + 0] += a1.x * il; sb[q * 132 + 1 * 32 + n4 * 4 + 1] += a1.y * il;
        sb[q * 132 + 1 * 32 + n4 * 4 + 2] += a1.z * il; sb[q * 132 + 1 * 32 + n4 * 4 + 3] += a1.w * il;
        sb[q * 132 + 2 * 32 + n4 * 4 + 0] += a2.x * il; sb[q * 132 + 2 * 32 + n4 * 4 + 1] += a2.y * il;
        sb[q * 132 + 2 * 32 + n4 * 4 + 2] += a2.z * il; sb[q * 132 + 2 * 32 + n4 * 4 + 3] += a2.w * il;
        sb[q * 132 + 3 * 32 + n4 * 4 + 0] += a3.x * il; sb[q * 132 + 3 * 32 + n4 * 4 + 1] += a3.y * il;
        sb[q * 132 + 3 * 32 + n4 * 4 + 2] += a3.z * il; sb[q * 132 + 3 * 32 + n4 * 4 + 3] += a3.w * il;
    }
    __syncthreads();

    // ---- ctx: ctx[q][m] = sum_tk sum_n W2_[bm(tq,tk)][h][n][m] * sb[q][tk][n] ----
    int m = tid & 31, qq = tid >> 5;  // qq 0..7
#pragma unroll
    for (int rep = 0; rep < 2; rep++) {
        int qi = qq + 8 * rep;
        int tq = qty_l[qi];
        float acc = 0.f;
#pragma unroll
        for (int tk2 = 0; tk2 < 4; tk2++) {
            int bmv = bm_of(tq, tk2);
            const float* wb = &W2s[((bmv * NH + h) * HD) * HD + m];
            const float* sbp = &sb[qi * 132 + tk2 * 32];
            for (int n = 0; n < HD; n++) acc += sbp[n] * wb[n * HD];
        }
        int qo = qor_l[qi];
        ctx[((long)(b * LL + qo)) * EMB + h * HD + m] = acc;
    }
}

// ---------------- K3: residual + LayerNorm (dtype-adaptive in/out) ----------------
__global__ void k_ln(const float* __restrict__ ctx, const void* __restrict__ x,
                     const void* __restrict__ gamma, const void* __restrict__ beta,
                     void* __restrict__ out, const int* __restrict__ fl) {
    __shared__ float red[8];
    __shared__ float red2[8];
    int isf = *fl;
    int blk = blockIdx.x;
    int b = blk >> 9, l = blk & 511;
    int j = threadIdx.x;
    long base = ((long)(b * LL + l)) * EMB;
    float v = ctx[base + j] + ldf(x, base + j, isf);
    float s = v, s2 = v * v;
    for (int off = 32; off > 0; off >>= 1) { s += __shfl_down(s, off, 64); s2 += __shfl_down(s2, off, 64); }
    int wid = j >> 6;
    if ((j & 63) == 0) { red[wid] = s; red2[wid] = s2; }
    __syncthreads();
    if (j == 0) {
        float ts = 0, ts2 = 0;
        for (int w = 0; w < 4; w++) { ts += red[w]; ts2 += red2[w]; }
        red[4] = ts; red2[4] = ts2;
    }
    __syncthreads();
    float mu = red[4] / (float)EMB;
    float var = red2[4] / (float)EMB - mu * mu;
    float r = rsqrtf(var + 1e-12f);
    float o = (v - mu) * r * ldf(gamma, j, isf) + ldf(beta, j, isf);
    if (isf) ((float*)out)[base + j] = o;
    else     ((bf16*)out)[base + j] = __float2bfloat16(o);
}

extern "C" void kernel_launch(void* const* d_in, const int* in_sizes, int n_in,
                              void* d_out, int out_size, void* d_ws, size_t ws_size,
                              hipStream_t stream) {
    const void* x  = d_in[0];
    const void* am = d_in[1];
    const int*  ts = (const int*)d_in[2];
    const void* Wq = d_in[3];
    const void* Wk = d_in[4];
    const void* Wv = d_in[5];
    const void* W1 = d_in[6];
    const void* a1 = d_in[7];
    const void* W2 = d_in[8];
    const void* a2 = d_in[9];
    const void* rp = d_in[10];
    const void* g  = d_in[11];
    const void* be = d_in[12];

    // workspace layout (~9.1 MB), all fp32 intermediates
    float* ws   = (float*)d_ws;
    int*   flag = (int*)ws;                    // 256 f slot (alignment pad)
    float* W1s  = ws + 256;                    // 81920 f
    float* W2s  = W1s + 81920;                 // 81920 f
    int*   tbl  = (int*)(W2s + 81920);         // 512 i
    int*   perm = tbl + 512;                   // 2048 i
    int*  ptype = perm + BB * LL;              // 2048 i
    float* qp   = (float*)(ptype + BB * LL);   // 524288 f
    float* kp   = qp + BB * NH * LL * HD;      // 524288 f
    float* vp   = kp + BB * NH * LL * HD;      // 524288 f
    float* ctx  = vp + BB * NH * LL * HD;      // 524288 f

    hipLaunchKernelGGL(k_flag, dim3(1), dim3(512), 0, stream, Wq, flag);
    hipLaunchKernelGGL(k_prep, dim3(161), dim3(256), 0, stream, a1, W1, a2, W2, W1s, W2s, tbl, flag);
    hipLaunchKernelGGL(k_perm, dim3(BB), dim3(LL), 0, stream, ts, perm, ptype);
    hipLaunchKernelGGL(k_qkv, dim3(3 * BB * 64), dim3(256), 0, stream, x, perm, ptype, Wq, Wk, Wv, qp, kp, vp, flag);
    hipLaunchKernelGGL(k_attn, dim3(BB * NH * 32), dim3(256), 0, stream, qp, kp, vp, perm, ptype, tbl, rp, am, W1s, W2s, ctx, flag);
    hipLaunchKernelGGL(k_ln, dim3(BB * LL), dim3(256), 0, stream, ctx, x, g, be, d_out, flag);
}

// Round 4
// 240.506 us; speedup vs baseline: 1.6248x; 1.6248x over previous
//
#include <hip/hip_runtime.h>
#include <math.h>

#define BB 4
#define LL 512
#define EMB 256
#define NH 8
#define HD 32
#define NB_ 3
#define CCN 10
#define NBKT 32
#define SCALE 0.17677669529663687f

__device__ __forceinline__ unsigned short f2b(float f) {
    unsigned int u = __float_as_uint(f);
    u += 0x7FFF + ((u >> 16) & 1);   // RNE
    return (unsigned short)(u >> 16);
}
__device__ __forceinline__ float b2f(unsigned short s) {
    return __uint_as_float(((unsigned int)s) << 16);
}
__device__ __forceinline__ int bm_of(int tq, int tk) {
    return (tq * tk != 0) ? ((tq - 1) * 3 + tk) : 0;
}
__device__ __forceinline__ unsigned long long shfl_up64(unsigned long long v, int d) {
    unsigned lo = (unsigned)__shfl_up((int)(unsigned)v, d, 64);
    unsigned hi = (unsigned)__shfl_up((int)(v >> 32), d, 64);
    return (((unsigned long long)hi) << 32) | lo;
}

// Stable counting sort of 512 tokens by type (4 types), 256 threads.
// spk[pos] = (type<<16) | orig_index. Deterministic -> identical across blocks.
// Uses 2 __syncthreads.
__device__ __forceinline__ void sort512(const int* __restrict__ tsb, int* spk,
                                        unsigned long long* wtll, int tid) {
    int ty0 = tsb[2 * tid], ty1 = tsb[2 * tid + 1];
    unsigned long long pk = (1ULL << (16 * ty0)) + (1ULL << (16 * ty1));
    unsigned long long v = pk;
    int lane = tid & 63;
#pragma unroll
    for (int off = 1; off < 64; off <<= 1) {
        unsigned long long o = shfl_up64(v, off);
        if (lane >= off) v += o;
    }
    int w = tid >> 6;
    if (lane == 63) wtll[w] = v;
    __syncthreads();
    unsigned long long pre = 0, tot = 0;
#pragma unroll
    for (int i = 0; i < 4; i++) {
        unsigned long long xx = wtll[i];
        if (i < w) pre += xx;
        tot += xx;
    }
    v += pre;
    unsigned long long excl = v - pk;
    int c0 = (int)(tot & 0xFFFF), c1 = (int)((tot >> 16) & 0xFFFF), c2 = (int)((tot >> 32) & 0xFFFF);
    int bases[4] = {0, c0, c0 + c1, c0 + c1 + c2};
    int r0 = (int)((excl >> (16 * ty0)) & 0xFFFF);
    unsigned long long excl1 = excl + (1ULL << (16 * ty0));
    int r1 = (int)((excl1 >> (16 * ty1)) & 0xFFFF);
    spk[bases[ty0] + r0] = (ty0 << 16) | (2 * tid);
    spk[bases[ty1] + r1] = (ty1 << 16) | (2 * tid + 1);
    __syncthreads();
}

// ---------------- K1: QKV projection (sorted order) + W1_/W2_ alpha-combine ----------------
// blocks 0..767: qkv (which=g/256, b=(g%256)/64, 8 sorted tokens each)
// blocks 768..927: weight combine (as old k_prep)
__global__ void k_qkv(const float* __restrict__ x, const int* __restrict__ ts,
                      const float* __restrict__ Wq, const float* __restrict__ Wk, const float* __restrict__ Wv,
                      const float* __restrict__ A1, const float* __restrict__ W1,
                      const float* __restrict__ A2, const float* __restrict__ W2,
                      float* __restrict__ qp, float* __restrict__ kp, float* __restrict__ vp,
                      float* __restrict__ W1s, float* __restrict__ W2s) {
    int g = blockIdx.x, tid = threadIdx.x;
    if (g >= 768) {  // ---- weight combine ----
        int idx = g - 768;
        const float* alpha = (idx < 80) ? A1 : A2;
        const float* W     = (idx < 80) ? W1 : W2;
        float* Ws          = (idx < 80) ? W1s : W2s;
        idx %= 80;
        int cc = idx / NH, h = idx % NH;
        float a0 = alpha[cc * NB_ * NH + 0 * NH + h];
        float a1 = alpha[cc * NB_ * NH + 1 * NH + h];
        float a2 = alpha[cc * NB_ * NH + 2 * NH + h];
        float mx = fmaxf(a0, fmaxf(a1, a2));
        float e0 = __expf(a0 - mx), e1 = __expf(a1 - mx), e2 = __expf(a2 - mx);
        float inv = 1.0f / (e0 + e1 + e2);
        e0 *= inv; e1 *= inv; e2 *= inv;
        for (int i = tid; i < HD * HD; i += 256) {
            int m = i >> 5, n = i & 31;
            float acc = e0 * W[((0 * NH + h) * HD + m) * HD + n]
                      + e1 * W[((1 * NH + h) * HD + m) * HD + n]
                      + e2 * W[((2 * NH + h) * HD + m) * HD + n];
            Ws[((cc * NH + h) * HD + m) * HD + n] = acc;
        }
        return;
    }
    __shared__ float xs[8][EMB];
    __shared__ int spk[LL];
    __shared__ unsigned long long wtll[4];
    int which = g >> 8;          // 0=q 1=k 2=v
    int rem = g & 255;
    int b = rem >> 6, i0 = (rem & 63) * 8;

    sort512(ts + b * LL, spk, wtll, tid);

    int tok[8], tloc[8];
#pragma unroll
    for (int tt = 0; tt < 8; tt++) {
        int v = spk[i0 + tt];
        tok[tt] = v & 0xFFFF; tloc[tt] = v >> 16;
    }
    // stage 8 token rows (float4)
    for (int i = tid; i < 8 * 64; i += 256) {
        int tt = i >> 6, e4 = i & 63;
        *(float4*)&xs[tt][e4 * 4] = *(const float4*)&x[(size_t)(b * LL + tok[tt]) * EMB + e4 * 4];
    }
    __syncthreads();

    const float* W = (which == 0) ? Wq : (which == 1 ? Wk : Wv);
    float* outp    = (which == 0) ? qp : (which == 1 ? kp : vp);
    int j = tid;
    float acc[8];
#pragma unroll
    for (int tt = 0; tt < 8; tt++) acc[tt] = 0.f;
    bool uni = true;
#pragma unroll
    for (int tt = 1; tt < 8; tt++) uni = uni && (tloc[tt] == tloc[0]);
    if (uni) {
        const float* wb = W + (size_t)tloc[0] * EMB * EMB + j;
        for (int e0 = 0; e0 < EMB; e0 += 4) {
            float w0 = wb[(e0 + 0) * EMB];
            float w1 = wb[(e0 + 1) * EMB];
            float w2 = wb[(e0 + 2) * EMB];
            float w3 = wb[(e0 + 3) * EMB];
#pragma unroll
            for (int tt = 0; tt < 8; tt++) {
                float4 xv = *(const float4*)&xs[tt][e0];
                acc[tt] += xv.x * w0 + xv.y * w1 + xv.z * w2 + xv.w * w3;
            }
        }
    } else {
        for (int tt = 0; tt < 8; tt++) {
            const float* wb = W + (size_t)tloc[tt] * EMB * EMB + j;
            float a = 0.f;
            for (int e = 0; e < EMB; e++) a += xs[tt][e] * wb[e * EMB];
            acc[tt] = a;
        }
    }
    int h = j >> 5, d = j & 31;
#pragma unroll
    for (int tt = 0; tt < 8; tt++)
        outp[((b * NH + h) * LL + i0 + tt) * HD + d] = acc[tt];
}

// ---------------- K2: attention core (self-contained) ----------------
// grid: BB*NH*32 blocks (16 queries each), 256 threads, 39,680 B LDS -> 4 blocks/CU.
#define SM_TOTAL 39680
__global__ __launch_bounds__(256, 4) void k_attn(
    const float* __restrict__ qp, const float* __restrict__ kp, const float* __restrict__ vp,
    const int* __restrict__ ts, const float* __restrict__ rp, const float* __restrict__ am,
    const float* __restrict__ W1s, const float* __restrict__ W2s,
    float* __restrict__ ctx) {
    __shared__ __align__(16) char smem[SM_TOTAL];
    unsigned short* scu = (unsigned short*)smem;            // [16*520]  16640 B
    float* kv   = (float*)(smem + 16640);                   // union: q-stage / kbuf(64x36) / vbuf(64x32) / sb(16x132)  9216 B
    float* qt_l = (float*)(smem + 25856);                   // [16*4*36] 9216 B
    float* rp_l = (float*)(smem + 35072);                   // [320]     1280 B
    int*   spk  = (int*)(smem + 36352);                     // [512]     2048 B
    short* tbl  = (short*)(smem + 38400);                   // [512]     1024 B
    unsigned long long* wtll = (unsigned long long*)(smem + 39424);  // 32 B
    int*   qor_l = (int*)(smem + 39456);                    // [16]
    int*   qty_l = (int*)(smem + 39520);                    // [16]
    float* inv_l = (float*)(smem + 39584);                  // [16]

    int blk = blockIdx.x;
    int b = blk >> 8, h = (blk >> 5) & 7, q16 = blk & 31;
    int i0q = q16 * 16;
    int tid = threadIdx.x;
    int bh = b * NH + h;

    // bucket table (double log, matches ref int-truncation)
    for (int d = tid; d < LL; d += 256) {
        int v;
        if (d < 8) v = d;
        else {
            double r = log((double)d / 8.0) / log(5.0);
            v = 8 + (int)(r * 8.0);
            if (v > 15) v = 15;
        }
        tbl[d] = (short)v;
    }
    for (int i = tid; i < CCN * NBKT; i += 256) rp_l[i] = rp[i * NH + h];

    sort512(ts + b * LL, spk, wtll, tid);   // barrier also publishes tbl/rp_l

    if (tid < 16) {
        int v = spk[i0q + tid];
        qor_l[tid] = v & 0xFFFF; qty_l[tid] = v >> 16;
    }
    // stage 16 q rows into kv
    for (int i = tid; i < 16 * 8; i += 256) {
        int q = i >> 3, m4 = i & 7;
        *(float4*)&kv[q * 32 + m4 * 4] = *(const float4*)&qp[((bh * LL) + i0q + q) * HD + m4 * 4];
    }
    __syncthreads();

    // fused qt: qt[q][tk][n] = sum_m q[m] * W1_[bm(tq,tk)][h][m][n]
    for (int i = tid; i < 16 * 128; i += 256) {
        int q = i >> 7, r = i & 127, tk = r >> 5, n = r & 31;
        int bmv = bm_of(qty_l[q], tk);
        const float* wb = &W1s[((bmv * NH + h) * HD) * HD + n];
        const float* qr = &kv[q * 32];
        float acc = 0.f;
#pragma unroll
        for (int m = 0; m < HD; m++) acc += qr[m] * wb[m * HD];
        qt_l[(q * 4 + tk) * 36 + n] = acc;
    }
    __syncthreads();

    // ---- pass 1: scores (bf16 into scu) ----
    int k = tid & 63, qg = tid >> 6;
    for (int kt0 = 0; kt0 < LL; kt0 += 64) {
        for (int i = tid; i < 64 * 8; i += 256) {   // kbuf pitch 36
            int kk = i >> 3, m4 = i & 7;
            *(float4*)&kv[kk * 36 + m4 * 4] = *(const float4*)&kp[(bh * LL + kt0 + kk) * HD + m4 * 4];
        }
        __syncthreads();
        int kpi = kt0 + k;
        int pv = spk[kpi];
        int ko = pv & 0xFFFF, tk = pv >> 16;
        float4 kr[8];
#pragma unroll
        for (int mm = 0; mm < 8; mm++) kr[mm] = *(const float4*)&kv[k * 36 + mm * 4];
        int ad_base = ko;  // for distance
        const float* amrow_b = am + (size_t)b * LL * LL + ko;
#pragma unroll
        for (int i = 0; i < 4; i++) {
            int q = qg * 4 + i;
            int tq = qty_l[q];
            int bmv = bm_of(tq, tk);
            const float* qrow = &qt_l[(q * 4 + tk) * 36];
            float s = 0.f;
#pragma unroll
            for (int mm = 0; mm < 8; mm++) {
                float4 qv = *(const float4*)&qrow[mm * 4];
                s += qv.x * kr[mm].x + qv.y * kr[mm].y + qv.z * kr[mm].z + qv.w * kr[mm].w;
            }
            int qo = qor_l[q];
            int dd = qo - ad_base;
            int ad = dd < 0 ? -dd : dd;
            int bk = (dd < 0 ? 16 : 0) + (int)tbl[ad];
            float bias = rp_l[bmv * NBKT + bk];
            float mval = amrow_b[(size_t)qo * LL];
            scu[q * 520 + kpi] = f2b(s * SCALE + bias + mval);
        }
        __syncthreads();
    }

    // ---- pass 2: softmax (16 threads / query) ----
    {
        int gq = tid >> 4, t16 = tid & 15;
        float mx = -1e30f;
        for (int j = 0; j < 32; j++) mx = fmaxf(mx, b2f(scu[gq * 520 + t16 + 16 * j]));
#pragma unroll
        for (int off = 1; off < 16; off <<= 1) mx = fmaxf(mx, __shfl_xor(mx, off, 16));
        float sum = 0.f;
        for (int j = 0; j < 32; j++) {
            int idx = gq * 520 + t16 + 16 * j;
            float e = __expf(b2f(scu[idx]) - mx);
            scu[idx] = f2b(e); sum += e;
        }
#pragma unroll
        for (int off = 1; off < 16; off <<= 1) sum += __shfl_xor(sum, off, 16);
        if (t16 == 0) inv_l[gq] = 1.0f / sum;
    }
    __syncthreads();

    // ---- pass 3: typed-bucket accumulation ----
    int n4 = tid & 7, q = (tid >> 3) & 15, khalf = tid >> 7;
    float4 a0 = make_float4(0, 0, 0, 0), a1 = a0, a2 = a0, a3 = a0;
    for (int kt0 = 0; kt0 < LL; kt0 += 64) {
        for (int i = tid; i < 64 * 8; i += 256) {   // vbuf pitch 32
            int kk = i >> 3, m4 = i & 7;
            *(float4*)&kv[kk * 32 + m4 * 4] = *(const float4*)&vp[(bh * LL + kt0 + kk) * HD + m4 * 4];
        }
        __syncthreads();
        for (int kk2 = 0; kk2 < 32; kk2++) {
            int kk = khalf * 32 + kk2;
            int kpi = kt0 + kk;
            int tk = spk[kpi] >> 16;    // wave-uniform
            float p = b2f(scu[q * 520 + kpi]);
            float4 v4 = *(const float4*)&kv[kk * 32 + n4 * 4];
            switch (tk) {
                case 0: a0.x += p * v4.x; a0.y += p * v4.y; a0.z += p * v4.z; a0.w += p * v4.w; break;
                case 1: a1.x += p * v4.x; a1.y += p * v4.y; a1.z += p * v4.z; a1.w += p * v4.w; break;
                case 2: a2.x += p * v4.x; a2.y += p * v4.y; a2.z += p * v4.z; a2.w += p * v4.w; break;
                default: a3.x += p * v4.x; a3.y += p * v4.y; a3.z += p * v4.z; a3.w += p * v4.w; break;
            }
        }
        __syncthreads();
    }
    float il = inv_l[q];
    float* sb = kv;  // vbuf dead now
    if (khalf == 0) {
        *(float4*)&sb[q * 132 +  0 + n4 * 4] = make_float4(a0.x * il, a0.y * il, a0.z * il, a0.w * il);
        *(float4*)&sb[q * 132 + 32 + n4 * 4] = make_float4(a1.x * il, a1.y * il, a1.z * il, a1.w * il);
        *(float4*)&sb[q * 132 + 64 + n4 * 4] = make_float4(a2.x * il, a2.y * il, a2.z * il, a2.w * il);
        *(float4*)&sb[q * 132 + 96 + n4 * 4] = make_float4(a3.x * il, a3.y * il, a3.z * il, a3.w * il);
    }
    __syncthreads();
    if (khalf == 1) {
#pragma unroll
        for (int c = 0; c < 4; c++) {
            float4 add = (c == 0) ? a0 : (c == 1) ? a1 : (c == 2) ? a2 : a3;
            float* p4 = &sb[q * 132 + c * 32 + n4 * 4];
            p4[0] += add.x * il; p4[1] += add.y * il; p4[2] += add.z * il; p4[3] += add.w * il;
        }
    }
    __syncthreads();

    // ---- ctx epilogue ----
    int m = tid & 31, qq = tid >> 5;
#pragma unroll
    for (int rep = 0; rep < 2; rep++) {
        int qi = qq + 8 * rep;
        int tq = qty_l[qi];
        float acc = 0.f;
#pragma unroll
        for (int tk2 = 0; tk2 < 4; tk2++) {
            int bmv = bm_of(tq, tk2);
            const float* wb = &W2s[((bmv * NH + h) * HD) * HD + m];
            const float* sbp = &sb[qi * 132 + tk2 * 32];
            for (int n = 0; n < HD; n++) acc += sbp[n] * wb[n * HD];
        }
        int qo = qor_l[qi];
        ctx[((size_t)(b * LL + qo)) * EMB + h * HD + m] = acc;
    }
}

// ---------------- K3: residual + LayerNorm ----------------
__global__ void k_ln(const float* __restrict__ ctx, const float* __restrict__ x,
                     const float* __restrict__ gamma, const float* __restrict__ beta,
                     float* __restrict__ out) {
    __shared__ float red[8];
    __shared__ float red2[8];
    int blk = blockIdx.x;
    int b = blk >> 9, l = blk & 511;
    int j = threadIdx.x;
    size_t base = ((size_t)(b * LL + l)) * EMB;
    float v = ctx[base + j] + x[base + j];
    float s = v, s2 = v * v;
    for (int off = 32; off > 0; off >>= 1) { s += __shfl_down(s, off, 64); s2 += __shfl_down(s2, off, 64); }
    int wid = j >> 6;
    if ((j & 63) == 0) { red[wid] = s; red2[wid] = s2; }
    __syncthreads();
    if (j == 0) {
        float ts_ = 0, ts2 = 0;
        for (int w = 0; w < 4; w++) { ts_ += red[w]; ts2 += red2[w]; }
        red[4] = ts_; red2[4] = ts2;
    }
    __syncthreads();
    float mu = red[4] / (float)EMB;
    float var = red2[4] / (float)EMB - mu * mu;
    float r = rsqrtf(var + 1e-12f);
    out[base + j] = (v - mu) * r * gamma[j] + beta[j];
}

extern "C" void kernel_launch(void* const* d_in, const int* in_sizes, int n_in,
                              void* d_out, int out_size, void* d_ws, size_t ws_size,
                              hipStream_t stream) {
    const float* x  = (const float*)d_in[0];
    const float* am = (const float*)d_in[1];
    const int*   ts = (const int*)d_in[2];
    const float* Wq = (const float*)d_in[3];
    const float* Wk = (const float*)d_in[4];
    const float* Wv = (const float*)d_in[5];
    const float* W1 = (const float*)d_in[6];
    const float* a1 = (const float*)d_in[7];
    const float* W2 = (const float*)d_in[8];
    const float* a2 = (const float*)d_in[9];
    const float* rp = (const float*)d_in[10];
    const float* g  = (const float*)d_in[11];
    const float* be = (const float*)d_in[12];
    float* out = (float*)d_out;

    float* ws  = (float*)d_ws;
    float* W1s = ws;                       // 81920 f
    float* W2s = ws + 81920;               // 81920 f
    float* qp  = ws + 163840;              // 524288 f
    float* kp  = qp + BB * NH * LL * HD;
    float* vp  = kp + BB * NH * LL * HD;
    float* ctx = vp + BB * NH * LL * HD;   // total ~9 MB

    hipLaunchKernelGGL(k_qkv, dim3(928), dim3(256), 0, stream,
                       x, ts, Wq, Wk, Wv, a1, W1, a2, W2, qp, kp, vp, W1s, W2s);
    hipLaunchKernelGGL(k_attn, dim3(BB * NH * 32), dim3(256), 0, stream,
                       qp, kp, vp, ts, rp, am, W1s, W2s, ctx);
    hipLaunchKernelGGL(k_ln, dim3(BB * LL), dim3(256), 0, stream, ctx, x, g, be, out);
}

// Round 5
// 178.946 us; speedup vs baseline: 2.1838x; 1.3440x over previous
//
#include <hip/hip_runtime.h>
#include <math.h>

#define BB 4
#define LL 512
#define EMB 256
#define NH 8
#define HD 32
#define NB_ 3
#define CCN 10
#define NBKT 32
#define SCALE 0.17677669529663687f

typedef __bf16 bf16_t;
typedef __attribute__((ext_vector_type(8))) bf16_t bf16x8;
typedef __attribute__((ext_vector_type(4))) float f32x4;

__device__ __forceinline__ unsigned short f2b(float f) {
    unsigned int u = __float_as_uint(f);
    u += 0x7FFF + ((u >> 16) & 1);   // RNE
    return (unsigned short)(u >> 16);
}
__device__ __forceinline__ float b2f(unsigned short s) {
    return __uint_as_float(((unsigned int)s) << 16);
}
__device__ __forceinline__ unsigned pack2(float a, float b) {
    return (unsigned)f2b(a) | ((unsigned)f2b(b) << 16);
}
__device__ __forceinline__ int bm_of(int tq, int tk) {
    return (tq * tk != 0) ? ((tq - 1) * 3 + tk) : 0;
}
__device__ __forceinline__ unsigned long long shfl_up64(unsigned long long v, int d) {
    unsigned lo = (unsigned)__shfl_up((int)(unsigned)v, d, 64);
    unsigned hi = (unsigned)__shfl_up((int)(v >> 32), d, 64);
    return (((unsigned long long)hi) << 32) | lo;
}

// Stable counting sort of 512 tokens by type (4 types), 256 threads.
// spk[pos] = (type<<16) | orig_index. Also publishes msc[]:
// [0..3]=padded segment bases pb, [4..7]=unpadded bases ub, [8..11]=counts c,
// [12]=KTOT (padded total, multiple of 64, <=640). 2 barriers.
__device__ __forceinline__ void sort512(const int* __restrict__ tsb, int* spk,
                                        unsigned long long* wtll, int* msc, int tid) {
    int ty0 = tsb[2 * tid], ty1 = tsb[2 * tid + 1];
    unsigned long long pk = (1ULL << (16 * ty0)) + (1ULL << (16 * ty1));
    unsigned long long v = pk;
    int lane = tid & 63;
#pragma unroll
    for (int off = 1; off < 64; off <<= 1) {
        unsigned long long o = shfl_up64(v, off);
        if (lane >= off) v += o;
    }
    int w = tid >> 6;
    if (lane == 63) wtll[w] = v;
    __syncthreads();
    unsigned long long pre = 0, tot = 0;
#pragma unroll
    for (int i = 0; i < 4; i++) {
        unsigned long long xx = wtll[i];
        if (i < w) pre += xx;
        tot += xx;
    }
    v += pre;
    unsigned long long excl = v - pk;
    int c0 = (int)(tot & 0xFFFF), c1 = (int)((tot >> 16) & 0xFFFF);
    int c2 = (int)((tot >> 32) & 0xFFFF), c3 = (int)((tot >> 48) & 0xFFFF);
    int ub0 = 0, ub1 = c0, ub2 = c0 + c1, ub3 = c0 + c1 + c2;
    if (tid == 0) {
        int pc0 = (c0 + 31) & ~31, pc1 = (c1 + 31) & ~31, pc2 = (c2 + 31) & ~31, pc3 = (c3 + 31) & ~31;
        int pb1 = pc0, pb2 = pc0 + pc1, pb3 = pc0 + pc1 + pc2;
        msc[0] = 0;  msc[1] = pb1; msc[2] = pb2; msc[3] = pb3;
        msc[4] = ub0; msc[5] = ub1; msc[6] = ub2; msc[7] = ub3;
        msc[8] = c0; msc[9] = c1; msc[10] = c2; msc[11] = c3;
        msc[12] = (pb3 + pc3 + 63) & ~63;
    }
    int bases[4] = {ub0, ub1, ub2, ub3};
    int r0 = (int)((excl >> (16 * ty0)) & 0xFFFF);
    unsigned long long excl1 = excl + (1ULL << (16 * ty0));
    int r1 = (int)((excl1 >> (16 * ty1)) & 0xFFFF);
    spk[bases[ty0] + r0] = (ty0 << 16) | (2 * tid);
    spk[bases[ty1] + r1] = (ty1 << 16) | (2 * tid + 1);
    __syncthreads();
}

// padded pos -> (real, upos). msc published.
__device__ __forceinline__ void pad_lookup(const int* msc, int pos, int& real, int& upos, int& seg) {
    seg = (pos >= msc[1]) + (pos >= msc[2]) + (pos >= msc[3]);
    int r = pos - msc[seg];
    real = (r < msc[8 + seg]) ? 1 : 0;
    upos = msc[4 + seg] + r;
}

// ---------------- K1: QKV projection (sorted order) + W1_/W2_ alpha-combine ----------------
__global__ void k_qkv(const float* __restrict__ x, const int* __restrict__ ts,
                      const float* __restrict__ Wq, const float* __restrict__ Wk, const float* __restrict__ Wv,
                      const float* __restrict__ A1, const float* __restrict__ W1,
                      const float* __restrict__ A2, const float* __restrict__ W2,
                      float* __restrict__ qp, float* __restrict__ kp, float* __restrict__ vp,
                      float* __restrict__ W1s, float* __restrict__ W2s) {
    int g = blockIdx.x, tid = threadIdx.x;
    if (g >= 768) {  // ---- weight combine ----
        int idx = g - 768;
        const float* alpha = (idx < 80) ? A1 : A2;
        const float* W     = (idx < 80) ? W1 : W2;
        float* Ws          = (idx < 80) ? W1s : W2s;
        idx %= 80;
        int cc = idx / NH, h = idx % NH;
        float a0 = alpha[cc * NB_ * NH + 0 * NH + h];
        float a1 = alpha[cc * NB_ * NH + 1 * NH + h];
        float a2 = alpha[cc * NB_ * NH + 2 * NH + h];
        float mx = fmaxf(a0, fmaxf(a1, a2));
        float e0 = __expf(a0 - mx), e1 = __expf(a1 - mx), e2 = __expf(a2 - mx);
        float inv = 1.0f / (e0 + e1 + e2);
        e0 *= inv; e1 *= inv; e2 *= inv;
        for (int i = tid; i < HD * HD; i += 256) {
            int m = i >> 5, n = i & 31;
            float acc = e0 * W[((0 * NH + h) * HD + m) * HD + n]
                      + e1 * W[((1 * NH + h) * HD + m) * HD + n]
                      + e2 * W[((2 * NH + h) * HD + m) * HD + n];
            Ws[((cc * NH + h) * HD + m) * HD + n] = acc;
        }
        return;
    }
    __shared__ float xs[8][EMB];
    __shared__ int spk[LL];
    __shared__ unsigned long long wtll[4];
    __shared__ int msc2[16];
    int which = g >> 8;
    int rem = g & 255;
    int b = rem >> 6, i0 = (rem & 63) * 8;

    sort512(ts + b * LL, spk, wtll, msc2, tid);

    int tok[8], tloc[8];
#pragma unroll
    for (int tt = 0; tt < 8; tt++) {
        int v = spk[i0 + tt];
        tok[tt] = v & 0xFFFF; tloc[tt] = v >> 16;
    }
    for (int i = tid; i < 8 * 64; i += 256) {
        int tt = i >> 6, e4 = i & 63;
        *(float4*)&xs[tt][e4 * 4] = *(const float4*)&x[(size_t)(b * LL + tok[tt]) * EMB + e4 * 4];
    }
    __syncthreads();

    const float* W = (which == 0) ? Wq : (which == 1 ? Wk : Wv);
    float* outp    = (which == 0) ? qp : (which == 1 ? kp : vp);
    int j = tid;
    float acc[8];
#pragma unroll
    for (int tt = 0; tt < 8; tt++) acc[tt] = 0.f;
    bool uni = true;
#pragma unroll
    for (int tt = 1; tt < 8; tt++) uni = uni && (tloc[tt] == tloc[0]);
    if (uni) {
        const float* wb = W + (size_t)tloc[0] * EMB * EMB + j;
        for (int e0 = 0; e0 < EMB; e0 += 4) {
            float w0 = wb[(e0 + 0) * EMB];
            float w1 = wb[(e0 + 1) * EMB];
            float w2 = wb[(e0 + 2) * EMB];
            float w3 = wb[(e0 + 3) * EMB];
#pragma unroll
            for (int tt = 0; tt < 8; tt++) {
                float4 xv = *(const float4*)&xs[tt][e0];
                acc[tt] += xv.x * w0 + xv.y * w1 + xv.z * w2 + xv.w * w3;
            }
        }
    } else {
        for (int tt = 0; tt < 8; tt++) {
            const float* wb = W + (size_t)tloc[tt] * EMB * EMB + j;
            float a = 0.f;
            for (int e = 0; e < EMB; e++) a += xs[tt][e] * wb[e * EMB];
            acc[tt] = a;
        }
    }
    int h = j >> 5, d = j & 31;
#pragma unroll
    for (int tt = 0; tt < 8; tt++)
        outp[((b * NH + h) * LL + i0 + tt) * HD + d] = acc[tt];
}

// ---------------- K2: attention core, MFMA edition ----------------
// grid: BB*NH*32 blocks (16 queries each), 256 threads = 4 waves. LDS 38,688 B -> 4 blocks/CU.
#define SCP 648            // scu pitch (ushorts), mult of 8
#define OFF_UN   20736
#define OFF_QTB  29184
#define OFF_KPAD 33536
#define OFF_TBL  36096
#define OFF_RPL  37120
#define OFF_WT   38400
#define OFF_QOR  38432
#define OFF_QTY  38496
#define OFF_INV  38560
#define OFF_MSC  38624
#define SM_TOTAL 38688
__global__ __launch_bounds__(256, 4) void k_attn(
    const float* __restrict__ qp, const float* __restrict__ kp, const float* __restrict__ vp,
    const int* __restrict__ ts, const float* __restrict__ rp, const float* __restrict__ am,
    const float* __restrict__ W1s, const float* __restrict__ W2s,
    float* __restrict__ ctx) {
    __shared__ __align__(16) char smem[SM_TOTAL];
    unsigned short* scu = (unsigned short*)smem;               // [16*648] bf16 scores/probs
    int*   spk  = (int*)smem;                                  // [512] aliases scu (dead before pass1)
    float* qst  = (float*)(smem + OFF_UN);                     // [16*32] q fp32 (prologue)
    unsigned short* kbuf = (unsigned short*)(smem + OFF_UN);   // [64*40] bf16 K tiles (pass1)
    unsigned short* vt   = (unsigned short*)(smem + OFF_UN);   // [32*72] bf16 V^T (pass3)
    float* sb   = (float*)(smem + OFF_UN);                     // [16*132] fp32 buckets (epilogue)
    unsigned short* qtb = (unsigned short*)(smem + OFF_QTB);   // [16*136] bf16 qt
    int*   kpad = (int*)(smem + OFF_KPAD);                     // [640] (ty<<16)|orig or |0xFFFF
    short* tbl  = (short*)(smem + OFF_TBL);                    // [512]
    float* rp_l = (float*)(smem + OFF_RPL);                    // [320]
    unsigned long long* wtll = (unsigned long long*)(smem + OFF_WT);
    int*   qor_l = (int*)(smem + OFF_QOR);
    int*   qty_l = (int*)(smem + OFF_QTY);
    float* inv_l = (float*)(smem + OFF_INV);
    int*   msc   = (int*)(smem + OFF_MSC);

    int blk = blockIdx.x;
    int b = blk >> 8, h = (blk >> 5) & 7, q16 = blk & 31;
    int i0q = q16 * 16;
    int tid = threadIdx.x;
    int wave = tid >> 6, lane = tid & 63, quad = lane >> 4, col = lane & 15;
    int bh = b * NH + h;

    for (int d = tid; d < LL; d += 256) {
        int v;
        if (d < 8) v = d;
        else {
            double r = log((double)d / 8.0) / log(5.0);
            v = 8 + (int)(r * 8.0);
            if (v > 15) v = 15;
        }
        tbl[d] = (short)v;
    }
    for (int i = tid; i < CCN * NBKT; i += 256) rp_l[i] = rp[i * NH + h];

    sort512(ts + b * LL, spk, wtll, msc, tid);   // publishes spk, msc (+tbl, rp_l)

    int KT = msc[12];                 // padded key count, mult of 64, <=640
    if (tid < 16) {
        int v = spk[i0q + tid];
        qor_l[tid] = v & 0xFFFF; qty_l[tid] = v >> 16;
    }
    // build kpad (padded key table); spk dead afterwards
    for (int pos = tid; pos < KT; pos += 256) {
        int real, upos, seg;
        pad_lookup(msc, pos, real, upos, seg);
        kpad[pos] = real ? spk[upos] : ((seg << 16) | 0xFFFF);
    }
    // stage 16 q rows fp32
    for (int i = tid; i < 16 * 8; i += 256) {
        int q = i >> 3, m4 = (i & 7) * 4;
        *(float4*)&qst[q * 32 + m4] = *(const float4*)&qp[((size_t)bh * LL + i0q + q) * HD + m4];
    }
    __syncthreads();

    int qor_r[4], qty_r[4];
#pragma unroll
    for (int r = 0; r < 4; r++) { qor_r[r] = qor_l[quad * 4 + r]; qty_r[r] = qty_l[quad * 4 + r]; }

    // ---- qt (bf16): qt[q][tk][n] = sum_m q[m] * W1_[bm(tq,tk)][h][m][n] ----
    for (int i = tid; i < 16 * 128; i += 256) {
        int q = i >> 7, r = i & 127, tk = r >> 5, n = r & 31;
        int bmv = bm_of(qty_l[q], tk);
        const float* wb = &W1s[((bmv * NH + h) * HD) * HD + n];
        const float* qr = &qst[q * 32];
        float acc = 0.f;
#pragma unroll
        for (int m = 0; m < HD; m++) acc += qr[m] * wb[m * HD];
        qtb[q * 136 + tk * 32 + n] = f2b(acc);
    }
    __syncthreads();

    // ---- pass 1: scores via MFMA, bf16 into scu ----
    const float* amb = am + (size_t)b * LL * LL;
    for (int kt0 = 0; kt0 < KT; kt0 += 64) {
        {   // stage 64 keys -> kbuf bf16 (pitch 40)
            int kk = tid >> 2, m8 = (tid & 3) * 8;
            int real, upos, seg;
            pad_lookup(msc, kt0 + kk, real, upos, seg);
            uint4 w = make_uint4(0, 0, 0, 0);
            if (real) {
                const float4* src = (const float4*)&kp[((size_t)bh * LL + upos) * HD + m8];
                float4 v0 = src[0], v1 = src[1];
                w.x = pack2(v0.x, v0.y); w.y = pack2(v0.z, v0.w);
                w.z = pack2(v1.x, v1.y); w.w = pack2(v1.z, v1.w);
            }
            *(uint4*)&kbuf[kk * 40 + m8] = w;
        }
        __syncthreads();
        {   // each wave: one 16-key tile
            int kb = kt0 + wave * 16;
            int tk = kpad[kb] >> 16;
            bf16x8 a = *(const bf16x8*)&qtb[col * 136 + tk * 32 + quad * 8];
            bf16x8 bfr = *(const bf16x8*)&kbuf[(wave * 16 + col) * 40 + quad * 8];
            f32x4 d = {0.f, 0.f, 0.f, 0.f};
            d = __builtin_amdgcn_mfma_f32_16x16x32_bf16(a, bfr, d, 0, 0, 0);
            int kpi = kb + col;
            int kv = kpad[kpi];
            int ko = kv & 0xFFFF;
            if (ko == 0xFFFF) {
#pragma unroll
                for (int r = 0; r < 4; r++) scu[(quad * 4 + r) * SCP + kpi] = 0xFF80;  // -inf
            } else {
                int tkk = kv >> 16;
#pragma unroll
                for (int r = 0; r < 4; r++) {
                    int q = quad * 4 + r;
                    int qo = qor_r[r];
                    int dd = qo - ko;
                    int ad = dd < 0 ? -dd : dd;
                    int bk = (dd < 0 ? 16 : 0) + (int)tbl[ad];
                    float bias = rp_l[bm_of(qty_r[r], tkk) * NBKT + bk];
                    float mval = amb[(size_t)qo * LL + ko];
                    scu[q * SCP + kpi] = f2b(d[r] * SCALE + bias + mval);
                }
            }
        }
        __syncthreads();
    }

    // ---- pass 2: softmax (16 threads / query) ----
    {
        int gq = tid >> 4, t16 = tid & 15;
        float mx = -1e30f;
        for (int kk = t16; kk < KT; kk += 16) mx = fmaxf(mx, b2f(scu[gq * SCP + kk]));
#pragma unroll
        for (int off = 1; off < 16; off <<= 1) mx = fmaxf(mx, __shfl_xor(mx, off, 16));
        float sum = 0.f;
        for (int kk = t16; kk < KT; kk += 16) {
            int idx = gq * SCP + kk;
            float e = __expf(b2f(scu[idx]) - mx);
            scu[idx] = f2b(e); sum += e;
        }
#pragma unroll
        for (int off = 1; off < 16; off <<= 1) sum += __shfl_xor(sum, off, 16);
        if (t16 == 0) inv_l[gq] = 1.0f / sum;
    }
    __syncthreads();

    // ---- pass 3: PV via MFMA into per-type accumulators ----
    f32x4 accv[4][2];
#pragma unroll
    for (int t = 0; t < 4; t++)
#pragma unroll
        for (int hh = 0; hh < 2; hh++) accv[t][hh] = (f32x4){0.f, 0.f, 0.f, 0.f};

    for (int kt0 = 0; kt0 < KT; kt0 += 64) {
        {   // stage 64 keys -> vt bf16 transposed [n][k], pitch 72
            int kk = tid >> 2, n8 = (tid & 3) * 8;
            int real, upos, seg;
            pad_lookup(msc, kt0 + kk, real, upos, seg);
            float vv[8] = {0, 0, 0, 0, 0, 0, 0, 0};
            if (real) {
                const float4* src = (const float4*)&vp[((size_t)bh * LL + upos) * HD + n8];
                float4 v0 = src[0], v1 = src[1];
                vv[0] = v0.x; vv[1] = v0.y; vv[2] = v0.z; vv[3] = v0.w;
                vv[4] = v1.x; vv[5] = v1.y; vv[6] = v1.z; vv[7] = v1.w;
            }
#pragma unroll
            for (int i = 0; i < 8; i++) vt[(n8 + i) * 72 + kk] = f2b(vv[i]);
        }
        __syncthreads();
        int c = kt0 >> 6;
        int g0 = 2 * c;
#pragma unroll
        for (int gl = 0; gl < 2; gl++) {
            int g = g0 + gl;
            if ((g & 3) != wave) continue;
            int loc = gl * 32;
            int tk = kpad[kt0 + loc] >> 16;
            bf16x8 a = *(const bf16x8*)&scu[col * SCP + kt0 + loc + quad * 8];
            bf16x8 b0 = *(const bf16x8*)&vt[col * 72 + loc + quad * 8];
            bf16x8 b1 = *(const bf16x8*)&vt[(col + 16) * 72 + loc + quad * 8];
            if (tk == 0) {
                accv[0][0] = __builtin_amdgcn_mfma_f32_16x16x32_bf16(a, b0, accv[0][0], 0, 0, 0);
                accv[0][1] = __builtin_amdgcn_mfma_f32_16x16x32_bf16(a, b1, accv[0][1], 0, 0, 0);
            } else if (tk == 1) {
                accv[1][0] = __builtin_amdgcn_mfma_f32_16x16x32_bf16(a, b0, accv[1][0], 0, 0, 0);
                accv[1][1] = __builtin_amdgcn_mfma_f32_16x16x32_bf16(a, b1, accv[1][1], 0, 0, 0);
            } else if (tk == 2) {
                accv[2][0] = __builtin_amdgcn_mfma_f32_16x16x32_bf16(a, b0, accv[2][0], 0, 0, 0);
                accv[2][1] = __builtin_amdgcn_mfma_f32_16x16x32_bf16(a, b1, accv[2][1], 0, 0, 0);
            } else {
                accv[3][0] = __builtin_amdgcn_mfma_f32_16x16x32_bf16(a, b0, accv[3][0], 0, 0, 0);
                accv[3][1] = __builtin_amdgcn_mfma_f32_16x16x32_bf16(a, b1, accv[3][1], 0, 0, 0);
            }
        }
        __syncthreads();
    }

    // ---- cross-wave reduction into sb[16][132] (vt region dead) ----
#pragma unroll
    for (int w = 0; w < 4; w++) {
        if (wave == w) {
#pragma unroll
            for (int t = 0; t < 4; t++)
#pragma unroll
                for (int hh = 0; hh < 2; hh++)
#pragma unroll
                    for (int r = 0; r < 4; r++) {
                        int q = quad * 4 + r;
                        int n = col + 16 * hh;
                        float val = accv[t][hh][r];
                        if (w == 0) sb[q * 132 + t * 32 + n] = val;
                        else        sb[q * 132 + t * 32 + n] += val;
                    }
        }
        __syncthreads();
    }

    // ---- ctx epilogue: ctx[q][m] = il * sum_tk sum_n W2_[bm][h][n][m] * sb[q][tk][n] ----
    int m = tid & 31, qq = tid >> 5;
#pragma unroll
    for (int rep = 0; rep < 2; rep++) {
        int qi = qq + 8 * rep;
        int tq = qty_l[qi];
        float acc = 0.f;
#pragma unroll
        for (int tk2 = 0; tk2 < 4; tk2++) {
            int bmv = bm_of(tq, tk2);
            const float* wb = &W2s[((bmv * NH + h) * HD) * HD + m];
            const float* sbp = &sb[qi * 132 + tk2 * 32];
            for (int n = 0; n < HD; n++) acc += sbp[n] * wb[n * HD];
        }
        int qo = qor_l[qi];
        ctx[((size_t)(b * LL + qo)) * EMB + h * HD + m] = acc * inv_l[qi];
    }
}

// ---------------- K3: residual + LayerNorm ----------------
__global__ void k_ln(const float* __restrict__ ctx, const float* __restrict__ x,
                     const float* __restrict__ gamma, const float* __restrict__ beta,
                     float* __restrict__ out) {
    __shared__ float red[8];
    __shared__ float red2[8];
    int blk = blockIdx.x;
    int b = blk >> 9, l = blk & 511;
    int j = threadIdx.x;
    size_t base = ((size_t)(b * LL + l)) * EMB;
    float v = ctx[base + j] + x[base + j];
    float s = v, s2 = v * v;
    for (int off = 32; off > 0; off >>= 1) { s += __shfl_down(s, off, 64); s2 += __shfl_down(s2, off, 64); }
    int wid = j >> 6;
    if ((j & 63) == 0) { red[wid] = s; red2[wid] = s2; }
    __syncthreads();
    if (j == 0) {
        float ts_ = 0, ts2 = 0;
        for (int w = 0; w < 4; w++) { ts_ += red[w]; ts2 += red2[w]; }
        red[4] = ts_; red2[4] = ts2;
    }
    __syncthreads();
    float mu = red[4] / (float)EMB;
    float var = red2[4] / (float)EMB - mu * mu;
    float r = rsqrtf(var + 1e-12f);
    out[base + j] = (v - mu) * r * gamma[j] + beta[j];
}

extern "C" void kernel_launch(void* const* d_in, const int* in_sizes, int n_in,
                              void* d_out, int out_size, void* d_ws, size_t ws_size,
                              hipStream_t stream) {
    const float* x  = (const float*)d_in[0];
    const float* am = (const float*)d_in[1];
    const int*   ts = (const int*)d_in[2];
    const float* Wq = (const float*)d_in[3];
    const float* Wk = (const float*)d_in[4];
    const float* Wv = (const float*)d_in[5];
    const float* W1 = (const float*)d_in[6];
    const float* a1 = (const float*)d_in[7];
    const float* W2 = (const float*)d_in[8];
    const float* a2 = (const float*)d_in[9];
    const float* rp = (const float*)d_in[10];
    const float* g  = (const float*)d_in[11];
    const float* be = (const float*)d_in[12];
    float* out = (float*)d_out;

    float* ws  = (float*)d_ws;
    float* W1s = ws;                       // 81920 f
    float* W2s = ws + 81920;               // 81920 f
    float* qp  = ws + 163840;              // 524288 f
    float* kp  = qp + BB * NH * LL * HD;
    float* vp  = kp + BB * NH * LL * HD;
    float* ctx = vp + BB * NH * LL * HD;   // total ~9 MB

    hipLaunchKernelGGL(k_qkv, dim3(928), dim3(256), 0, stream,
                       x, ts, Wq, Wk, Wv, a1, W1, a2, W2, qp, kp, vp, W1s, W2s);
    hipLaunchKernelGGL(k_attn, dim3(BB * NH * 32), dim3(256), 0, stream,
                       qp, kp, vp, ts, rp, am, W1s, W2s, ctx);
    hipLaunchKernelGGL(k_ln, dim3(BB * LL), dim3(256), 0, stream, ctx, x, g, be, out);
}

// Round 6
// 155.541 us; speedup vs baseline: 2.5124x; 1.1505x over previous
//
#include <hip/hip_runtime.h>
#include <math.h>

#define BB 4
#define LL 512
#define EMB 256
#define NH 8
#define HD 32
#define NB_ 3
#define CCN 10
#define NBKT 32
#define SCALE 0.17677669529663687f

typedef __bf16 bf16_t;
typedef __attribute__((ext_vector_type(8))) bf16_t bf16x8;
typedef __attribute__((ext_vector_type(4))) float f32x4;

__device__ __forceinline__ unsigned short f2b(float f) {
    unsigned int u = __float_as_uint(f);
    u += 0x7FFF + ((u >> 16) & 1);   // RNE
    return (unsigned short)(u >> 16);
}
__device__ __forceinline__ float b2f(unsigned short s) {
    return __uint_as_float(((unsigned int)s) << 16);
}
__device__ __forceinline__ unsigned pack2(float a, float b) {
    return (unsigned)f2b(a) | ((unsigned)f2b(b) << 16);
}
__device__ __forceinline__ int bm_of(int tq, int tk) {
    return (tq * tk != 0) ? ((tq - 1) * 3 + tk) : 0;
}
__device__ __forceinline__ unsigned long long shfl_up64(unsigned long long v, int d) {
    unsigned lo = (unsigned)__shfl_up((int)(unsigned)v, d, 64);
    unsigned hi = (unsigned)__shfl_up((int)(v >> 32), d, 64);
    return (((unsigned long long)hi) << 32) | lo;
}

// Stable counting sort of 512 tokens by type (4 types), 256 threads.
// spk[pos] = (type<<16) | orig_index. msc: [0..3]=padded bases, [4..7]=unpadded
// bases, [8..11]=counts, [12]=KTOT (padded, mult of 64). 2 barriers.
__device__ __forceinline__ void sort512(const int* __restrict__ tsb, int* spk,
                                        unsigned long long* wtll, int* msc, int tid) {
    int ty0 = tsb[2 * tid], ty1 = tsb[2 * tid + 1];
    unsigned long long pk = (1ULL << (16 * ty0)) + (1ULL << (16 * ty1));
    unsigned long long v = pk;
    int lane = tid & 63;
#pragma unroll
    for (int off = 1; off < 64; off <<= 1) {
        unsigned long long o = shfl_up64(v, off);
        if (lane >= off) v += o;
    }
    int w = tid >> 6;
    if (lane == 63) wtll[w] = v;
    __syncthreads();
    unsigned long long pre = 0, tot = 0;
#pragma unroll
    for (int i = 0; i < 4; i++) {
        unsigned long long xx = wtll[i];
        if (i < w) pre += xx;
        tot += xx;
    }
    v += pre;
    unsigned long long excl = v - pk;
    int c0 = (int)(tot & 0xFFFF), c1 = (int)((tot >> 16) & 0xFFFF);
    int c2 = (int)((tot >> 32) & 0xFFFF), c3 = (int)((tot >> 48) & 0xFFFF);
    int ub0 = 0, ub1 = c0, ub2 = c0 + c1, ub3 = c0 + c1 + c2;
    if (tid == 0) {
        int pc0 = (c0 + 31) & ~31, pc1 = (c1 + 31) & ~31, pc2 = (c2 + 31) & ~31, pc3 = (c3 + 31) & ~31;
        int pb1 = pc0, pb2 = pc0 + pc1, pb3 = pc0 + pc1 + pc2;
        msc[0] = 0;  msc[1] = pb1; msc[2] = pb2; msc[3] = pb3;
        msc[4] = ub0; msc[5] = ub1; msc[6] = ub2; msc[7] = ub3;
        msc[8] = c0; msc[9] = c1; msc[10] = c2; msc[11] = c3;
        msc[12] = (pb3 + pc3 + 63) & ~63;
    }
    int bases[4] = {ub0, ub1, ub2, ub3};
    int r0 = (int)((excl >> (16 * ty0)) & 0xFFFF);
    unsigned long long excl1 = excl + (1ULL << (16 * ty0));
    int r1 = (int)((excl1 >> (16 * ty1)) & 0xFFFF);
    spk[bases[ty0] + r0] = (ty0 << 16) | (2 * tid);
    spk[bases[ty1] + r1] = (ty1 << 16) | (2 * tid + 1);
    __syncthreads();
}

__device__ __forceinline__ void pad_lookup(const int* msc, int pos, int& real, int& upos, int& seg) {
    seg = (pos >= msc[1]) + (pos >= msc[2]) + (pos >= msc[3]);
    int r = pos - msc[seg];
    real = (r < msc[8 + seg]) ? 1 : 0;
    upos = msc[4 + seg] + r;
}

// ---------------- K0: weight combine + QKV weight transpose (fp32 -> bf16) ----------------
// blocks 0..159: W1s/W2s alpha-combine. blocks 160..207: transpose Wq/Wk/Wv into
// Wt[which*4+ty][out][e] bf16.
__global__ void k_pre(const float* __restrict__ A1, const float* __restrict__ W1,
                      const float* __restrict__ A2, const float* __restrict__ W2,
                      const float* __restrict__ Wq, const float* __restrict__ Wk, const float* __restrict__ Wv,
                      float* __restrict__ W1s, float* __restrict__ W2s,
                      unsigned short* __restrict__ Wt) {
    int g = blockIdx.x, tid = threadIdx.x;
    if (g < 160) {
        int idx = g;
        const float* alpha = (idx < 80) ? A1 : A2;
        const float* W     = (idx < 80) ? W1 : W2;
        float* Ws          = (idx < 80) ? W1s : W2s;
        idx %= 80;
        int cc = idx / NH, h = idx % NH;
        float a0 = alpha[cc * NB_ * NH + 0 * NH + h];
        float a1 = alpha[cc * NB_ * NH + 1 * NH + h];
        float a2 = alpha[cc * NB_ * NH + 2 * NH + h];
        float mx = fmaxf(a0, fmaxf(a1, a2));
        float e0 = __expf(a0 - mx), e1 = __expf(a1 - mx), e2 = __expf(a2 - mx);
        float inv = 1.0f / (e0 + e1 + e2);
        e0 *= inv; e1 *= inv; e2 *= inv;
        for (int i = tid; i < HD * HD; i += 256) {
            int m = i >> 5, n = i & 31;
            float acc = e0 * W[((0 * NH + h) * HD + m) * HD + n]
                      + e1 * W[((1 * NH + h) * HD + m) * HD + n]
                      + e2 * W[((2 * NH + h) * HD + m) * HD + n];
            Ws[((cc * NH + h) * HD + m) * HD + n] = acc;
        }
        return;
    }
    int t = g - 160;             // 0..47
    int tw = t >> 2, eq = t & 3; // tw = which*4+ty
    int which = tw >> 2, ty = tw & 3;
    const float* src = ((which == 0) ? Wq : (which == 1) ? Wk : Wv) + (size_t)ty * EMB * EMB;
    unsigned short* dst = Wt + (size_t)tw * EMB * EMB;
    int out4 = (tid & 63) * 4;
    int e0 = eq * 64 + (tid >> 6) * 16;
    for (int i = 0; i < 16; i++) {
        int e = e0 + i;
        float4 v = *(const float4*)&src[(size_t)e * EMB + out4];
        dst[(size_t)(out4 + 0) * EMB + e] = f2b(v.x);
        dst[(size_t)(out4 + 1) * EMB + e] = f2b(v.y);
        dst[(size_t)(out4 + 2) * EMB + e] = f2b(v.z);
        dst[(size_t)(out4 + 3) * EMB + e] = f2b(v.w);
    }
}

// ---------------- K1: QKV projection as segment-wise MFMA GEMM ----------------
// grid 384: g -> (b, token-block of 32, ns) with ns = which*2+nh (128-out slice).
// 256 threads = 4 waves; each wave owns 2 N-tiles x 2 M-tiles.
__global__ __launch_bounds__(256, 4) void k_qkv(
    const float* __restrict__ x, const int* __restrict__ ts,
    const unsigned short* __restrict__ Wt,
    float* __restrict__ qp, float* __restrict__ kp, float* __restrict__ vp) {
    __shared__ int spk[LL];
    __shared__ unsigned long long wtll[4];
    __shared__ int msc[16];
    __shared__ unsigned short xs[32 * 264];   // 16,896 B (pitch 264: 2-way max)
    __shared__ unsigned short wt[128 * 72];   // 18,432 B (pitch 72: 2-way max)

    int g = blockIdx.x, tid = threadIdx.x;
    int ns = g % 6, gb = g / 6;
    int b = gb >> 4, tb = gb & 15, i0 = tb * 32;
    int which = ns >> 1, nh = ns & 1;
    int wave = tid >> 6, lane = tid & 63, quad = lane >> 4, col = lane & 15;

    sort512(ts + b * LL, spk, wtll, msc, tid);

    // stage 32 sorted token rows as bf16
    {
        int tok = tid >> 3, e32 = (tid & 7) * 32;
        int tok_orig = spk[i0 + tok] & 0xFFFF;
        const float* src = &x[(size_t)(b * LL + tok_orig) * EMB + e32];
        unsigned short* dstl = &xs[tok * 264 + e32];
#pragma unroll
        for (int jj = 0; jj < 4; jj++) {
            float4 v0 = *(const float4*)&src[jj * 8];
            float4 v1 = *(const float4*)&src[jj * 8 + 4];
            uint4 w;
            w.x = pack2(v0.x, v0.y); w.y = pack2(v0.z, v0.w);
            w.z = pack2(v1.x, v1.y); w.w = pack2(v1.z, v1.w);
            *(uint4*)&dstl[jj * 8] = w;
        }
    }
    int t_start = spk[i0] >> 16, t_end = spk[i0 + 31] >> 16;
    float* outp = (which == 0) ? qp : (which == 1) ? kp : vp;

    for (int ty = t_start; ty <= t_end; ty++) {
        f32x4 acc[2][2];
#pragma unroll
        for (int mt = 0; mt < 2; mt++)
#pragma unroll
            for (int nt = 0; nt < 2; nt++) acc[mt][nt] = (f32x4){0.f, 0.f, 0.f, 0.f};
        const unsigned short* wsrc = Wt + (size_t)(which * 4 + ty) * EMB * EMB + (size_t)(nh * 128) * EMB;
        for (int c = 0; c < 4; c++) {
            {   // stage W-tile chunk: 128 outs x 64 e
                int outloc = tid >> 1, e32 = (tid & 1) * 32;
                const unsigned short* srcw = &wsrc[(size_t)outloc * EMB + c * 64 + e32];
                unsigned short* dstw = &wt[outloc * 72 + e32];
#pragma unroll
                for (int jj = 0; jj < 4; jj++)
                    *(uint4*)&dstw[jj * 8] = *(const uint4*)&srcw[jj * 8];
            }
            __syncthreads();
#pragma unroll
            for (int kk = 0; kk < 2; kk++) {
                bf16x8 a0 = *(const bf16x8*)&xs[(0 * 16 + col) * 264 + c * 64 + kk * 32 + quad * 8];
                bf16x8 a1 = *(const bf16x8*)&xs[(1 * 16 + col) * 264 + c * 64 + kk * 32 + quad * 8];
                bf16x8 b0 = *(const bf16x8*)&wt[((wave * 2 + 0) * 16 + col) * 72 + kk * 32 + quad * 8];
                bf16x8 b1 = *(const bf16x8*)&wt[((wave * 2 + 1) * 16 + col) * 72 + kk * 32 + quad * 8];
                acc[0][0] = __builtin_amdgcn_mfma_f32_16x16x32_bf16(a0, b0, acc[0][0], 0, 0, 0);
                acc[0][1] = __builtin_amdgcn_mfma_f32_16x16x32_bf16(a0, b1, acc[0][1], 0, 0, 0);
                acc[1][0] = __builtin_amdgcn_mfma_f32_16x16x32_bf16(a1, b0, acc[1][0], 0, 0, 0);
                acc[1][1] = __builtin_amdgcn_mfma_f32_16x16x32_bf16(a1, b1, acc[1][1], 0, 0, 0);
            }
            __syncthreads();
        }
        // write rows of this type only
#pragma unroll
        for (int mt = 0; mt < 2; mt++)
#pragma unroll
            for (int r = 0; r < 4; r++) {
                int tokloc = mt * 16 + quad * 4 + r;
                int tty = spk[i0 + tokloc] >> 16;
                if (tty != ty) continue;
#pragma unroll
                for (int nt = 0; nt < 2; nt++) {
                    int n = nh * 128 + (wave * 2 + nt) * 16 + col;
                    int h = n >> 5, d = n & 31;
                    outp[((size_t)(b * NH + h) * LL + i0 + tokloc) * HD + d] = acc[mt][nt][r];
                }
            }
    }
}

// ---------------- K2: attention core, MFMA edition (unchanged from R5) ----------------
#define SCP 648
#define OFF_UN   20736
#define OFF_QTB  29184
#define OFF_KPAD 33536
#define OFF_TBL  36096
#define OFF_RPL  37120
#define OFF_WT   38400
#define OFF_QOR  38432
#define OFF_QTY  38496
#define OFF_INV  38560
#define OFF_MSC  38624
#define SM_TOTAL 38688
__global__ __launch_bounds__(256, 4) void k_attn(
    const float* __restrict__ qp, const float* __restrict__ kp, const float* __restrict__ vp,
    const int* __restrict__ ts, const float* __restrict__ rp, const float* __restrict__ am,
    const float* __restrict__ W1s, const float* __restrict__ W2s,
    float* __restrict__ ctx) {
    __shared__ __align__(16) char smem[SM_TOTAL];
    unsigned short* scu = (unsigned short*)smem;
    int*   spk  = (int*)smem;
    float* qst  = (float*)(smem + OFF_UN);
    unsigned short* kbuf = (unsigned short*)(smem + OFF_UN);
    unsigned short* vt   = (unsigned short*)(smem + OFF_UN);
    float* sb   = (float*)(smem + OFF_UN);
    unsigned short* qtb = (unsigned short*)(smem + OFF_QTB);
    int*   kpad = (int*)(smem + OFF_KPAD);
    short* tbl  = (short*)(smem + OFF_TBL);
    float* rp_l = (float*)(smem + OFF_RPL);
    unsigned long long* wtll = (unsigned long long*)(smem + OFF_WT);
    int*   qor_l = (int*)(smem + OFF_QOR);
    int*   qty_l = (int*)(smem + OFF_QTY);
    float* inv_l = (float*)(smem + OFF_INV);
    int*   msc   = (int*)(smem + OFF_MSC);

    int blk = blockIdx.x;
    int b = blk >> 8, h = (blk >> 5) & 7, q16 = blk & 31;
    int i0q = q16 * 16;
    int tid = threadIdx.x;
    int wave = tid >> 6, lane = tid & 63, quad = lane >> 4, col = lane & 15;
    int bh = b * NH + h;

    for (int d = tid; d < LL; d += 256) {
        int v;
        if (d < 8) v = d;
        else {
            double r = log((double)d / 8.0) / log(5.0);
            v = 8 + (int)(r * 8.0);
            if (v > 15) v = 15;
        }
        tbl[d] = (short)v;
    }
    for (int i = tid; i < CCN * NBKT; i += 256) rp_l[i] = rp[i * NH + h];

    sort512(ts + b * LL, spk, wtll, msc, tid);

    int KT = msc[12];
    if (tid < 16) {
        int v = spk[i0q + tid];
        qor_l[tid] = v & 0xFFFF; qty_l[tid] = v >> 16;
    }
    for (int pos = tid; pos < KT; pos += 256) {
        int real, upos, seg;
        pad_lookup(msc, pos, real, upos, seg);
        kpad[pos] = real ? spk[upos] : ((seg << 16) | 0xFFFF);
    }
    for (int i = tid; i < 16 * 8; i += 256) {
        int q = i >> 3, m4 = (i & 7) * 4;
        *(float4*)&qst[q * 32 + m4] = *(const float4*)&qp[((size_t)bh * LL + i0q + q) * HD + m4];
    }
    __syncthreads();

    int qor_r[4], qty_r[4];
#pragma unroll
    for (int r = 0; r < 4; r++) { qor_r[r] = qor_l[quad * 4 + r]; qty_r[r] = qty_l[quad * 4 + r]; }

    for (int i = tid; i < 16 * 128; i += 256) {
        int q = i >> 7, r = i & 127, tk = r >> 5, n = r & 31;
        int bmv = bm_of(qty_l[q], tk);
        const float* wb = &W1s[((bmv * NH + h) * HD) * HD + n];
        const float* qr = &qst[q * 32];
        float acc = 0.f;
#pragma unroll
        for (int m = 0; m < HD; m++) acc += qr[m] * wb[m * HD];
        qtb[q * 136 + tk * 32 + n] = f2b(acc);
    }
    __syncthreads();

    const float* amb = am + (size_t)b * LL * LL;
    for (int kt0 = 0; kt0 < KT; kt0 += 64) {
        {
            int kk = tid >> 2, m8 = (tid & 3) * 8;
            int real, upos, seg;
            pad_lookup(msc, kt0 + kk, real, upos, seg);
            uint4 w = make_uint4(0, 0, 0, 0);
            if (real) {
                const float4* src = (const float4*)&kp[((size_t)bh * LL + upos) * HD + m8];
                float4 v0 = src[0], v1 = src[1];
                w.x = pack2(v0.x, v0.y); w.y = pack2(v0.z, v0.w);
                w.z = pack2(v1.x, v1.y); w.w = pack2(v1.z, v1.w);
            }
            *(uint4*)&kbuf[kk * 40 + m8] = w;
        }
        __syncthreads();
        {
            int kb = kt0 + wave * 16;
            int tk = kpad[kb] >> 16;
            bf16x8 a = *(const bf16x8*)&qtb[col * 136 + tk * 32 + quad * 8];
            bf16x8 bfr = *(const bf16x8*)&kbuf[(wave * 16 + col) * 40 + quad * 8];
            f32x4 d = {0.f, 0.f, 0.f, 0.f};
            d = __builtin_amdgcn_mfma_f32_16x16x32_bf16(a, bfr, d, 0, 0, 0);
            int kpi = kb + col;
            int kv = kpad[kpi];
            int ko = kv & 0xFFFF;
            if (ko == 0xFFFF) {
#pragma unroll
                for (int r = 0; r < 4; r++) scu[(quad * 4 + r) * SCP + kpi] = 0xFF80;
            } else {
                int tkk = kv >> 16;
#pragma unroll
                for (int r = 0; r < 4; r++) {
                    int q = quad * 4 + r;
                    int qo = qor_r[r];
                    int dd = qo - ko;
                    int ad = dd < 0 ? -dd : dd;
                    int bk = (dd < 0 ? 16 : 0) + (int)tbl[ad];
                    float bias = rp_l[bm_of(qty_r[r], tkk) * NBKT + bk];
                    float mval = amb[(size_t)qo * LL + ko];
                    scu[q * SCP + kpi] = f2b(d[r] * SCALE + bias + mval);
                }
            }
        }
        __syncthreads();
    }

    {
        int gq = tid >> 4, t16 = tid & 15;
        float mx = -1e30f;
        for (int kk = t16; kk < KT; kk += 16) mx = fmaxf(mx, b2f(scu[gq * SCP + kk]));
#pragma unroll
        for (int off = 1; off < 16; off <<= 1) mx = fmaxf(mx, __shfl_xor(mx, off, 16));
        float sum = 0.f;
        for (int kk = t16; kk < KT; kk += 16) {
            int idx = gq * SCP + kk;
            float e = __expf(b2f(scu[idx]) - mx);
            scu[idx] = f2b(e); sum += e;
        }
#pragma unroll
        for (int off = 1; off < 16; off <<= 1) sum += __shfl_xor(sum, off, 16);
        if (t16 == 0) inv_l[gq] = 1.0f / sum;
    }
    __syncthreads();

    f32x4 accv[4][2];
#pragma unroll
    for (int t = 0; t < 4; t++)
#pragma unroll
        for (int hh = 0; hh < 2; hh++) accv[t][hh] = (f32x4){0.f, 0.f, 0.f, 0.f};

    for (int kt0 = 0; kt0 < KT; kt0 += 64) {
        {
            int kk = tid >> 2, n8 = (tid & 3) * 8;
            int real, upos, seg;
            pad_lookup(msc, kt0 + kk, real, upos, seg);
            float vv[8] = {0, 0, 0, 0, 0, 0, 0, 0};
            if (real) {
                const float4* src = (const float4*)&vp[((size_t)bh * LL + upos) * HD + n8];
                float4 v0 = src[0], v1 = src[1];
                vv[0] = v0.x; vv[1] = v0.y; vv[2] = v0.z; vv[3] = v0.w;
                vv[4] = v1.x; vv[5] = v1.y; vv[6] = v1.z; vv[7] = v1.w;
            }
#pragma unroll
            for (int i = 0; i < 8; i++) vt[(n8 + i) * 72 + kk] = f2b(vv[i]);
        }
        __syncthreads();
        int c = kt0 >> 6;
        int g0 = 2 * c;
#pragma unroll
        for (int gl = 0; gl < 2; gl++) {
            int g = g0 + gl;
            if ((g & 3) != wave) continue;
            int loc = gl * 32;
            int tk = kpad[kt0 + loc] >> 16;
            bf16x8 a = *(const bf16x8*)&scu[col * SCP + kt0 + loc + quad * 8];
            bf16x8 b0 = *(const bf16x8*)&vt[col * 72 + loc + quad * 8];
            bf16x8 b1 = *(const bf16x8*)&vt[(col + 16) * 72 + loc + quad * 8];
            if (tk == 0) {
                accv[0][0] = __builtin_amdgcn_mfma_f32_16x16x32_bf16(a, b0, accv[0][0], 0, 0, 0);
                accv[0][1] = __builtin_amdgcn_mfma_f32_16x16x32_bf16(a, b1, accv[0][1], 0, 0, 0);
            } else if (tk == 1) {
                accv[1][0] = __builtin_amdgcn_mfma_f32_16x16x32_bf16(a, b0, accv[1][0], 0, 0, 0);
                accv[1][1] = __builtin_amdgcn_mfma_f32_16x16x32_bf16(a, b1, accv[1][1], 0, 0, 0);
            } else if (tk == 2) {
                accv[2][0] = __builtin_amdgcn_mfma_f32_16x16x32_bf16(a, b0, accv[2][0], 0, 0, 0);
                accv[2][1] = __builtin_amdgcn_mfma_f32_16x16x32_bf16(a, b1, accv[2][1], 0, 0, 0);
            } else {
                accv[3][0] = __builtin_amdgcn_mfma_f32_16x16x32_bf16(a, b0, accv[3][0], 0, 0, 0);
                accv[3][1] = __builtin_amdgcn_mfma_f32_16x16x32_bf16(a, b1, accv[3][1], 0, 0, 0);
            }
        }
        __syncthreads();
    }

#pragma unroll
    for (int w = 0; w < 4; w++) {
        if (wave == w) {
#pragma unroll
            for (int t = 0; t < 4; t++)
#pragma unroll
                for (int hh = 0; hh < 2; hh++)
#pragma unroll
                    for (int r = 0; r < 4; r++) {
                        int q = quad * 4 + r;
                        int n = col + 16 * hh;
                        float val = accv[t][hh][r];
                        if (w == 0) sb[q * 132 + t * 32 + n] = val;
                        else        sb[q * 132 + t * 32 + n] += val;
                    }
        }
        __syncthreads();
    }

    int m = tid & 31, qq = tid >> 5;
#pragma unroll
    for (int rep = 0; rep < 2; rep++) {
        int qi = qq + 8 * rep;
        int tq = qty_l[qi];
        float acc = 0.f;
#pragma unroll
        for (int tk2 = 0; tk2 < 4; tk2++) {
            int bmv = bm_of(tq, tk2);
            const float* wb = &W2s[((bmv * NH + h) * HD) * HD + m];
            const float* sbp = &sb[qi * 132 + tk2 * 32];
            for (int n = 0; n < HD; n++) acc += sbp[n] * wb[n * HD];
        }
        int qo = qor_l[qi];
        ctx[((size_t)(b * LL + qo)) * EMB + h * HD + m] = acc * inv_l[qi];
    }
}

// ---------------- K3: residual + LayerNorm ----------------
__global__ void k_ln(const float* __restrict__ ctx, const float* __restrict__ x,
                     const float* __restrict__ gamma, const float* __restrict__ beta,
                     float* __restrict__ out) {
    __shared__ float red[8];
    __shared__ float red2[8];
    int blk = blockIdx.x;
    int b = blk >> 9, l = blk & 511;
    int j = threadIdx.x;
    size_t base = ((size_t)(b * LL + l)) * EMB;
    float v = ctx[base + j] + x[base + j];
    float s = v, s2 = v * v;
    for (int off = 32; off > 0; off >>= 1) { s += __shfl_down(s, off, 64); s2 += __shfl_down(s2, off, 64); }
    int wid = j >> 6;
    if ((j & 63) == 0) { red[wid] = s; red2[wid] = s2; }
    __syncthreads();
    if (j == 0) {
        float ts_ = 0, ts2 = 0;
        for (int w = 0; w < 4; w++) { ts_ += red[w]; ts2 += red2[w]; }
        red[4] = ts_; red2[4] = ts2;
    }
    __syncthreads();
    float mu = red[4] / (float)EMB;
    float var = red2[4] / (float)EMB - mu * mu;
    float r = rsqrtf(var + 1e-12f);
    out[base + j] = (v - mu) * r * gamma[j] + beta[j];
}

extern "C" void kernel_launch(void* const* d_in, const int* in_sizes, int n_in,
                              void* d_out, int out_size, void* d_ws, size_t ws_size,
                              hipStream_t stream) {
    const float* x  = (const float*)d_in[0];
    const float* am = (const float*)d_in[1];
    const int*   ts = (const int*)d_in[2];
    const float* Wq = (const float*)d_in[3];
    const float* Wk = (const float*)d_in[4];
    const float* Wv = (const float*)d_in[5];
    const float* W1 = (const float*)d_in[6];
    const float* a1 = (const float*)d_in[7];
    const float* W2 = (const float*)d_in[8];
    const float* a2 = (const float*)d_in[9];
    const float* rp = (const float*)d_in[10];
    const float* g  = (const float*)d_in[11];
    const float* be = (const float*)d_in[12];
    float* out = (float*)d_out;

    float* ws  = (float*)d_ws;
    float* W1s = ws;                       // 81920 f
    float* W2s = ws + 81920;               // 81920 f
    float* qp  = ws + 163840;              // 524288 f each
    float* kp  = qp + BB * NH * LL * HD;
    float* vp  = kp + BB * NH * LL * HD;
    float* ctx = vp + BB * NH * LL * HD;   // 524288 f (2 MB)
    // Wt (1.5 MB bf16) aliases ctx: live k_pre -> k_qkv; ctx written by k_attn afterwards.
    unsigned short* Wt = (unsigned short*)ctx;

    hipLaunchKernelGGL(k_pre, dim3(208), dim3(256), 0, stream,
                       a1, W1, a2, W2, Wq, Wk, Wv, W1s, W2s, Wt);
    hipLaunchKernelGGL(k_qkv, dim3(384), dim3(256), 0, stream, x, ts, Wt, qp, kp, vp);
    hipLaunchKernelGGL(k_attn, dim3(BB * NH * 32), dim3(256), 0, stream,
                       qp, kp, vp, ts, rp, am, W1s, W2s, ctx);
    hipLaunchKernelGGL(k_ln, dim3(BB * LL), dim3(256), 0, stream, ctx, x, g, be, out);
}

// Round 7
// 154.273 us; speedup vs baseline: 2.5330x; 1.0082x over previous
//
#include <hip/hip_runtime.h>
#include <math.h>

#define BB 4
#define LL 512
#define EMB 256
#define NH 8
#define HD 32
#define NB_ 3
#define CCN 10
#define NBKT 32
#define SCALE 0.17677669529663687f

typedef __bf16 bf16_t;
typedef __attribute__((ext_vector_type(8))) bf16_t bf16x8;
typedef __attribute__((ext_vector_type(4))) float f32x4;

__device__ __forceinline__ unsigned short f2b(float f) {
    unsigned int u = __float_as_uint(f);
    u += 0x7FFF + ((u >> 16) & 1);   // RNE
    return (unsigned short)(u >> 16);
}
__device__ __forceinline__ float b2f(unsigned short s) {
    return __uint_as_float(((unsigned int)s) << 16);
}
__device__ __forceinline__ unsigned pack2(float a, float b) {
    return (unsigned)f2b(a) | ((unsigned)f2b(b) << 16);
}
__device__ __forceinline__ int bm_of(int tq, int tk) {
    return (tq * tk != 0) ? ((tq - 1) * 3 + tk) : 0;
}
__device__ __forceinline__ unsigned long long shfl_up64(unsigned long long v, int d) {
    unsigned lo = (unsigned)__shfl_up((int)(unsigned)v, d, 64);
    unsigned hi = (unsigned)__shfl_up((int)(v >> 32), d, 64);
    return (((unsigned long long)hi) << 32) | lo;
}

// Stable counting sort of 512 tokens by type (4 types), 256 threads.
__device__ __forceinline__ void sort512(const int* __restrict__ tsb, int* spk,
                                        unsigned long long* wtll, int* msc, int tid) {
    int ty0 = tsb[2 * tid], ty1 = tsb[2 * tid + 1];
    unsigned long long pk = (1ULL << (16 * ty0)) + (1ULL << (16 * ty1));
    unsigned long long v = pk;
    int lane = tid & 63;
#pragma unroll
    for (int off = 1; off < 64; off <<= 1) {
        unsigned long long o = shfl_up64(v, off);
        if (lane >= off) v += o;
    }
    int w = tid >> 6;
    if (lane == 63) wtll[w] = v;
    __syncthreads();
    unsigned long long pre = 0, tot = 0;
#pragma unroll
    for (int i = 0; i < 4; i++) {
        unsigned long long xx = wtll[i];
        if (i < w) pre += xx;
        tot += xx;
    }
    v += pre;
    unsigned long long excl = v - pk;
    int c0 = (int)(tot & 0xFFFF), c1 = (int)((tot >> 16) & 0xFFFF);
    int c2 = (int)((tot >> 32) & 0xFFFF), c3 = (int)((tot >> 48) & 0xFFFF);
    int ub0 = 0, ub1 = c0, ub2 = c0 + c1, ub3 = c0 + c1 + c2;
    if (tid == 0) {
        int pc0 = (c0 + 31) & ~31, pc1 = (c1 + 31) & ~31, pc2 = (c2 + 31) & ~31, pc3 = (c3 + 31) & ~31;
        int pb1 = pc0, pb2 = pc0 + pc1, pb3 = pc0 + pc1 + pc2;
        msc[0] = 0;  msc[1] = pb1; msc[2] = pb2; msc[3] = pb3;
        msc[4] = ub0; msc[5] = ub1; msc[6] = ub2; msc[7] = ub3;
        msc[8] = c0; msc[9] = c1; msc[10] = c2; msc[11] = c3;
        msc[12] = (pb3 + pc3 + 63) & ~63;
    }
    int bases[4] = {ub0, ub1, ub2, ub3};
    int r0 = (int)((excl >> (16 * ty0)) & 0xFFFF);
    unsigned long long excl1 = excl + (1ULL << (16 * ty0));
    int r1 = (int)((excl1 >> (16 * ty1)) & 0xFFFF);
    spk[bases[ty0] + r0] = (ty0 << 16) | (2 * tid);
    spk[bases[ty1] + r1] = (ty1 << 16) | (2 * tid + 1);
    __syncthreads();
}

__device__ __forceinline__ void pad_lookup(const int* msc, int pos, int& real, int& upos, int& seg) {
    seg = (pos >= msc[1]) + (pos >= msc[2]) + (pos >= msc[3]);
    int r = pos - msc[seg];
    real = (r < msc[8 + seg]) ? 1 : 0;
    upos = msc[4 + seg] + r;
}

// ---------------- K0: weight combine + QKV weight transpose (via LDS, coalesced out) ----------------
__global__ void k_pre(const float* __restrict__ A1, const float* __restrict__ W1,
                      const float* __restrict__ A2, const float* __restrict__ W2,
                      const float* __restrict__ Wq, const float* __restrict__ Wk, const float* __restrict__ Wv,
                      float* __restrict__ W1s, float* __restrict__ W2s,
                      unsigned short* __restrict__ Wt) {
    int g = blockIdx.x, tid = threadIdx.x;
    if (g < 160) {
        int idx = g;
        const float* alpha = (idx < 80) ? A1 : A2;
        const float* W     = (idx < 80) ? W1 : W2;
        float* Ws          = (idx < 80) ? W1s : W2s;
        idx %= 80;
        int cc = idx / NH, h = idx % NH;
        float a0 = alpha[cc * NB_ * NH + 0 * NH + h];
        float a1 = alpha[cc * NB_ * NH + 1 * NH + h];
        float a2 = alpha[cc * NB_ * NH + 2 * NH + h];
        float mx = fmaxf(a0, fmaxf(a1, a2));
        float e0 = __expf(a0 - mx), e1 = __expf(a1 - mx), e2 = __expf(a2 - mx);
        float inv = 1.0f / (e0 + e1 + e2);
        e0 *= inv; e1 *= inv; e2 *= inv;
        for (int i = tid; i < HD * HD; i += 256) {
            int m = i >> 5, n = i & 31;
            float acc = e0 * W[((0 * NH + h) * HD + m) * HD + n]
                      + e1 * W[((1 * NH + h) * HD + m) * HD + n]
                      + e2 * W[((2 * NH + h) * HD + m) * HD + n];
            Ws[((cc * NH + h) * HD + m) * HD + n] = acc;
        }
        return;
    }
    // transpose blocks: 48 = 12 tw x 4 out-blocks of 64
    __shared__ unsigned short ls[64 * 264];   // 33,792 B
    int t = g - 160;
    int tw = t >> 2, ob = t & 3;
    int which = tw >> 2, ty = tw & 3;
    const float* src = ((which == 0) ? Wq : (which == 1) ? Wk : Wv) + (size_t)ty * EMB * EMB;
    int out0 = ob * 64;
    for (int it = 0; it < 16; it++) {
        int e = it * 16 + (tid >> 4);
        int o4 = (tid & 15) * 4;
        float4 v = *(const float4*)&src[(size_t)e * EMB + out0 + o4];
        ls[(o4 + 0) * 264 + e] = f2b(v.x);
        ls[(o4 + 1) * 264 + e] = f2b(v.y);
        ls[(o4 + 2) * 264 + e] = f2b(v.z);
        ls[(o4 + 3) * 264 + e] = f2b(v.w);
    }
    __syncthreads();
    int out = tid >> 2, ech = (tid & 3) * 8;
    unsigned short* dst = Wt + (size_t)tw * EMB * EMB + (size_t)(out0 + out) * EMB;
    const unsigned short* srcl = &ls[out * 264];
#pragma unroll
    for (int jj = 0; jj < 8; jj++)
        *(uint4*)&dst[ech + jj * 32] = *(const uint4*)&srcl[ech + jj * 32];
}

// ---------------- K1: QKV projection as segment-wise MFMA GEMM (unchanged from R6) ----------------
__global__ __launch_bounds__(256, 4) void k_qkv(
    const float* __restrict__ x, const int* __restrict__ ts,
    const unsigned short* __restrict__ Wt,
    float* __restrict__ qp, float* __restrict__ kp, float* __restrict__ vp) {
    __shared__ int spk[LL];
    __shared__ unsigned long long wtll[4];
    __shared__ int msc[16];
    __shared__ unsigned short xs[32 * 264];
    __shared__ unsigned short wt[128 * 72];

    int g = blockIdx.x, tid = threadIdx.x;
    int ns = g % 6, gb = g / 6;
    int b = gb >> 4, tb = gb & 15, i0 = tb * 32;
    int which = ns >> 1, nh = ns & 1;
    int wave = tid >> 6, lane = tid & 63, quad = lane >> 4, col = lane & 15;

    sort512(ts + b * LL, spk, wtll, msc, tid);

    {
        int tok = tid >> 3, e32 = (tid & 7) * 32;
        int tok_orig = spk[i0 + tok] & 0xFFFF;
        const float* src = &x[(size_t)(b * LL + tok_orig) * EMB + e32];
        unsigned short* dstl = &xs[tok * 264 + e32];
#pragma unroll
        for (int jj = 0; jj < 4; jj++) {
            float4 v0 = *(const float4*)&src[jj * 8];
            float4 v1 = *(const float4*)&src[jj * 8 + 4];
            uint4 w;
            w.x = pack2(v0.x, v0.y); w.y = pack2(v0.z, v0.w);
            w.z = pack2(v1.x, v1.y); w.w = pack2(v1.z, v1.w);
            *(uint4*)&dstl[jj * 8] = w;
        }
    }
    int t_start = spk[i0] >> 16, t_end = spk[i0 + 31] >> 16;
    float* outp = (which == 0) ? qp : (which == 1) ? kp : vp;

    for (int ty = t_start; ty <= t_end; ty++) {
        f32x4 acc[2][2];
#pragma unroll
        for (int mt = 0; mt < 2; mt++)
#pragma unroll
            for (int nt = 0; nt < 2; nt++) acc[mt][nt] = (f32x4){0.f, 0.f, 0.f, 0.f};
        const unsigned short* wsrc = Wt + (size_t)(which * 4 + ty) * EMB * EMB + (size_t)(nh * 128) * EMB;
        for (int c = 0; c < 4; c++) {
            {
                int outloc = tid >> 1, e32 = (tid & 1) * 32;
                const unsigned short* srcw = &wsrc[(size_t)outloc * EMB + c * 64 + e32];
                unsigned short* dstw = &wt[outloc * 72 + e32];
#pragma unroll
                for (int jj = 0; jj < 4; jj++)
                    *(uint4*)&dstw[jj * 8] = *(const uint4*)&srcw[jj * 8];
            }
            __syncthreads();
#pragma unroll
            for (int kk = 0; kk < 2; kk++) {
                bf16x8 a0 = *(const bf16x8*)&xs[(0 * 16 + col) * 264 + c * 64 + kk * 32 + quad * 8];
                bf16x8 a1 = *(const bf16x8*)&xs[(1 * 16 + col) * 264 + c * 64 + kk * 32 + quad * 8];
                bf16x8 b0 = *(const bf16x8*)&wt[((wave * 2 + 0) * 16 + col) * 72 + kk * 32 + quad * 8];
                bf16x8 b1 = *(const bf16x8*)&wt[((wave * 2 + 1) * 16 + col) * 72 + kk * 32 + quad * 8];
                acc[0][0] = __builtin_amdgcn_mfma_f32_16x16x32_bf16(a0, b0, acc[0][0], 0, 0, 0);
                acc[0][1] = __builtin_amdgcn_mfma_f32_16x16x32_bf16(a0, b1, acc[0][1], 0, 0, 0);
                acc[1][0] = __builtin_amdgcn_mfma_f32_16x16x32_bf16(a1, b0, acc[1][0], 0, 0, 0);
                acc[1][1] = __builtin_amdgcn_mfma_f32_16x16x32_bf16(a1, b1, acc[1][1], 0, 0, 0);
            }
            __syncthreads();
        }
#pragma unroll
        for (int mt = 0; mt < 2; mt++)
#pragma unroll
            for (int r = 0; r < 4; r++) {
                int tokloc = mt * 16 + quad * 4 + r;
                int tty = spk[i0 + tokloc] >> 16;
                if (tty != ty) continue;
#pragma unroll
                for (int nt = 0; nt < 2; nt++) {
                    int n = nh * 128 + (wave * 2 + nt) * 16 + col;
                    int h = n >> 5, d = n & 31;
                    outp[((size_t)(b * NH + h) * LL + i0 + tokloc) * HD + d] = acc[mt][nt][r];
                }
            }
    }
}

// ---------------- K2: attention core, MFMA + pass0 bias/mask prefill + vt row-perm ----------------
#define SCP 648
#define OFF_UN   20736
#define OFF_QTB  29184
#define OFF_KPAD 33536
#define OFF_TBL  36096
#define OFF_RPL  37120
#define OFF_WT   38400
#define OFF_QOR  38432
#define OFF_QTY  38496
#define OFF_INV  38560
#define OFF_MSC  38624
#define SM_TOTAL 38688
__global__ __launch_bounds__(256, 4) void k_attn(
    const float* __restrict__ qp, const float* __restrict__ kp, const float* __restrict__ vp,
    const int* __restrict__ ts, const float* __restrict__ rp, const float* __restrict__ am,
    const float* __restrict__ W1s, const float* __restrict__ W2s,
    float* __restrict__ ctx) {
    __shared__ __align__(16) char smem[SM_TOTAL];
    unsigned short* scu = (unsigned short*)smem;
    int*   spk  = (int*)smem;
    float* qst  = (float*)(smem + OFF_UN);
    unsigned short* kbuf = (unsigned short*)(smem + OFF_UN);
    unsigned short* vt   = (unsigned short*)(smem + OFF_UN);
    float* sb   = (float*)(smem + OFF_UN);
    unsigned short* qtb = (unsigned short*)(smem + OFF_QTB);
    int*   kpad = (int*)(smem + OFF_KPAD);
    short* tbl  = (short*)(smem + OFF_TBL);
    float* rp_l = (float*)(smem + OFF_RPL);
    unsigned long long* wtll = (unsigned long long*)(smem + OFF_WT);
    int*   qor_l = (int*)(smem + OFF_QOR);
    int*   qty_l = (int*)(smem + OFF_QTY);
    float* inv_l = (float*)(smem + OFF_INV);
    int*   msc   = (int*)(smem + OFF_MSC);

    int blk = blockIdx.x;
    int b = blk >> 8, h = (blk >> 5) & 7, q16 = blk & 31;
    int i0q = q16 * 16;
    int tid = threadIdx.x;
    int wave = tid >> 6, lane = tid & 63, quad = lane >> 4, col = lane & 15;
    int bh = b * NH + h;

    for (int d = tid; d < LL; d += 256) {
        int v;
        if (d < 8) v = d;
        else {
            double r = log((double)d / 8.0) / log(5.0);
            v = 8 + (int)(r * 8.0);
            if (v > 15) v = 15;
        }
        tbl[d] = (short)v;
    }
    for (int i = tid; i < CCN * NBKT; i += 256) rp_l[i] = rp[i * NH + h];

    sort512(ts + b * LL, spk, wtll, msc, tid);

    int KT = msc[12];
    if (tid < 16) {
        int v = spk[i0q + tid];
        qor_l[tid] = v & 0xFFFF; qty_l[tid] = v >> 16;
    }
    for (int pos = tid; pos < KT; pos += 256) {
        int real, upos, seg;
        pad_lookup(msc, pos, real, upos, seg);
        kpad[pos] = real ? spk[upos] : ((seg << 16) | 0xFFFF);
    }
    for (int i = tid; i < 16 * 8; i += 256) {
        int q = i >> 3, m4 = (i & 7) * 4;
        *(float4*)&qst[q * 32 + m4] = *(const float4*)&qp[((size_t)bh * LL + i0q + q) * HD + m4];
    }
    __syncthreads();

    // ---- qt (VALU) ----
    for (int i = tid; i < 16 * 128; i += 256) {
        int q = i >> 7, r = i & 127, tk = r >> 5, n = r & 31;
        int bmv = bm_of(qty_l[q], tk);
        const float* wb = &W1s[((bmv * NH + h) * HD) * HD + n];
        const float* qr = &qst[q * 32];
        float acc = 0.f;
#pragma unroll
        for (int m = 0; m < HD; m++) acc += qr[m] * wb[m * HD];
        qtb[q * 136 + tk * 32 + n] = f2b(acc);
    }

    // ---- pass 0: prefill scu with bias+mask (bf16); pads -> -inf. (spk dead; scu aliases it) ----
    const float* amb = am + (size_t)b * LL * LL;
    for (int q = 0; q < 16; q++) {
        int qo = qor_l[q], tq = qty_l[q];
        const float* amrow = amb + (size_t)qo * LL;
        for (int kpi = tid; kpi < KT; kpi += 256) {
            int kv = kpad[kpi];
            int ko = kv & 0xFFFF;
            unsigned short o;
            if (ko == 0xFFFF) o = 0xFF80;
            else {
                int tkk = kv >> 16;
                int dd = qo - ko;
                int ad = dd < 0 ? -dd : dd;
                int bk = (dd < 0 ? 16 : 0) + (int)tbl[ad];
                o = f2b(rp_l[bm_of(tq, tkk) * NBKT + bk] + amrow[ko]);
            }
            scu[q * SCP + kpi] = o;
        }
    }
    __syncthreads();

    // ---- pass 1: scores via MFMA, branch-free RMW epilogue ----
    for (int kt0 = 0; kt0 < KT; kt0 += 64) {
        {
            int kk = tid >> 2, m8 = (tid & 3) * 8;
            int real, upos, seg;
            pad_lookup(msc, kt0 + kk, real, upos, seg);
            uint4 w = make_uint4(0, 0, 0, 0);
            if (real) {
                const float4* src = (const float4*)&kp[((size_t)bh * LL + upos) * HD + m8];
                float4 v0 = src[0], v1 = src[1];
                w.x = pack2(v0.x, v0.y); w.y = pack2(v0.z, v0.w);
                w.z = pack2(v1.x, v1.y); w.w = pack2(v1.z, v1.w);
            }
            *(uint4*)&kbuf[kk * 40 + m8] = w;
        }
        __syncthreads();
        {
            int kb = kt0 + wave * 16;
            int tk = kpad[kb] >> 16;
            bf16x8 a = *(const bf16x8*)&qtb[col * 136 + tk * 32 + quad * 8];
            bf16x8 bfr = *(const bf16x8*)&kbuf[(wave * 16 + col) * 40 + quad * 8];
            f32x4 d = {0.f, 0.f, 0.f, 0.f};
            d = __builtin_amdgcn_mfma_f32_16x16x32_bf16(a, bfr, d, 0, 0, 0);
            int kpi = kb + col;
#pragma unroll
            for (int r = 0; r < 4; r++) {
                int idx = (quad * 4 + r) * SCP + kpi;
                scu[idx] = f2b(d[r] * SCALE + b2f(scu[idx]));
            }
        }
        __syncthreads();
    }

    // ---- pass 2: softmax (16 threads / query) ----
    {
        int gq = tid >> 4, t16 = tid & 15;
        float mx = -1e30f;
        for (int kk = t16; kk < KT; kk += 16) mx = fmaxf(mx, b2f(scu[gq * SCP + kk]));
#pragma unroll
        for (int off = 1; off < 16; off <<= 1) mx = fmaxf(mx, __shfl_xor(mx, off, 16));
        float sum = 0.f;
        for (int kk = t16; kk < KT; kk += 16) {
            int idx = gq * SCP + kk;
            float e = __expf(b2f(scu[idx]) - mx);
            scu[idx] = f2b(e); sum += e;
        }
#pragma unroll
        for (int off = 1; off < 16; off <<= 1) sum += __shfl_xor(sum, off, 16);
        if (t16 == 0) inv_l[gq] = 1.0f / sum;
    }
    __syncthreads();

    // ---- pass 3: PV via MFMA; vt rows permuted phys(n)=((n&3)<<3)|(n>>2) ----
    f32x4 accv[4][2];
#pragma unroll
    for (int t = 0; t < 4; t++)
#pragma unroll
        for (int hh = 0; hh < 2; hh++) accv[t][hh] = (f32x4){0.f, 0.f, 0.f, 0.f};

    for (int kt0 = 0; kt0 < KT; kt0 += 64) {
        {
            int kk = tid >> 2, n8 = (tid & 3) * 8;
            int real, upos, seg;
            pad_lookup(msc, kt0 + kk, real, upos, seg);
            float vv[8] = {0, 0, 0, 0, 0, 0, 0, 0};
            if (real) {
                const float4* src = (const float4*)&vp[((size_t)bh * LL + upos) * HD + n8];
                float4 v0 = src[0], v1 = src[1];
                vv[0] = v0.x; vv[1] = v0.y; vv[2] = v0.z; vv[3] = v0.w;
                vv[4] = v1.x; vv[5] = v1.y; vv[6] = v1.z; vv[7] = v1.w;
            }
#pragma unroll
            for (int i = 0; i < 8; i++) {
                int n = n8 + i;
                int ph = ((n & 3) << 3) | (n >> 2);
                vt[ph * 72 + kk] = f2b(vv[i]);
            }
        }
        __syncthreads();
        int c = kt0 >> 6;
        int g0 = 2 * c;
        int pc = ((col & 3) << 3) | (col >> 2);
#pragma unroll
        for (int gl = 0; gl < 2; gl++) {
            int g = g0 + gl;
            if ((g & 3) != wave) continue;
            int loc = gl * 32;
            int tk = kpad[kt0 + loc] >> 16;
            bf16x8 a = *(const bf16x8*)&scu[col * SCP + kt0 + loc + quad * 8];
            bf16x8 b0 = *(const bf16x8*)&vt[pc * 72 + loc + quad * 8];
            bf16x8 b1 = *(const bf16x8*)&vt[(pc + 4) * 72 + loc + quad * 8];
            if (tk == 0) {
                accv[0][0] = __builtin_amdgcn_mfma_f32_16x16x32_bf16(a, b0, accv[0][0], 0, 0, 0);
                accv[0][1] = __builtin_amdgcn_mfma_f32_16x16x32_bf16(a, b1, accv[0][1], 0, 0, 0);
            } else if (tk == 1) {
                accv[1][0] = __builtin_amdgcn_mfma_f32_16x16x32_bf16(a, b0, accv[1][0], 0, 0, 0);
                accv[1][1] = __builtin_amdgcn_mfma_f32_16x16x32_bf16(a, b1, accv[1][1], 0, 0, 0);
            } else if (tk == 2) {
                accv[2][0] = __builtin_amdgcn_mfma_f32_16x16x32_bf16(a, b0, accv[2][0], 0, 0, 0);
                accv[2][1] = __builtin_amdgcn_mfma_f32_16x16x32_bf16(a, b1, accv[2][1], 0, 0, 0);
            } else {
                accv[3][0] = __builtin_amdgcn_mfma_f32_16x16x32_bf16(a, b0, accv[3][0], 0, 0, 0);
                accv[3][1] = __builtin_amdgcn_mfma_f32_16x16x32_bf16(a, b1, accv[3][1], 0, 0, 0);
            }
        }
        __syncthreads();
    }

#pragma unroll
    for (int w = 0; w < 4; w++) {
        if (wave == w) {
#pragma unroll
            for (int t = 0; t < 4; t++)
#pragma unroll
                for (int hh = 0; hh < 2; hh++)
#pragma unroll
                    for (int r = 0; r < 4; r++) {
                        int q = quad * 4 + r;
                        int n = col + 16 * hh;
                        float val = accv[t][hh][r];
                        if (w == 0) sb[q * 132 + t * 32 + n] = val;
                        else        sb[q * 132 + t * 32 + n] += val;
                    }
        }
        __syncthreads();
    }

    int m = tid & 31, qq = tid >> 5;
#pragma unroll
    for (int rep = 0; rep < 2; rep++) {
        int qi = qq + 8 * rep;
        int tq = qty_l[qi];
        float acc = 0.f;
#pragma unroll
        for (int tk2 = 0; tk2 < 4; tk2++) {
            int bmv = bm_of(tq, tk2);
            const float* wb = &W2s[((bmv * NH + h) * HD) * HD + m];
            const float* sbp = &sb[qi * 132 + tk2 * 32];
            for (int n = 0; n < HD; n++) acc += sbp[n] * wb[n * HD];
        }
        int qo = qor_l[qi];
        ctx[((size_t)(b * LL + qo)) * EMB + h * HD + m] = acc * inv_l[qi];
    }
}

// ---------------- K3: residual + LayerNorm ----------------
__global__ void k_ln(const float* __restrict__ ctx, const float* __restrict__ x,
                     const float* __restrict__ gamma, const float* __restrict__ beta,
                     float* __restrict__ out) {
    __shared__ float red[8];
    __shared__ float red2[8];
    int blk = blockIdx.x;
    int b = blk >> 9, l = blk & 511;
    int j = threadIdx.x;
    size_t base = ((size_t)(b * LL + l)) * EMB;
    float v = ctx[base + j] + x[base + j];
    float s = v, s2 = v * v;
    for (int off = 32; off > 0; off >>= 1) { s += __shfl_down(s, off, 64); s2 += __shfl_down(s2, off, 64); }
    int wid = j >> 6;
    if ((j & 63) == 0) { red[wid] = s; red2[wid] = s2; }
    __syncthreads();
    if (j == 0) {
        float ts_ = 0, ts2 = 0;
        for (int w = 0; w < 4; w++) { ts_ += red[w]; ts2 += red2[w]; }
        red[4] = ts_; red2[4] = ts2;
    }
    __syncthreads();
    float mu = red[4] / (float)EMB;
    float var = red2[4] / (float)EMB - mu * mu;
    float r = rsqrtf(var + 1e-12f);
    out[base + j] = (v - mu) * r * gamma[j] + beta[j];
}

extern "C" void kernel_launch(void* const* d_in, const int* in_sizes, int n_in,
                              void* d_out, int out_size, void* d_ws, size_t ws_size,
                              hipStream_t stream) {
    const float* x  = (const float*)d_in[0];
    const float* am = (const float*)d_in[1];
    const int*   ts = (const int*)d_in[2];
    const float* Wq = (const float*)d_in[3];
    const float* Wk = (const float*)d_in[4];
    const float* Wv = (const float*)d_in[5];
    const float* W1 = (const float*)d_in[6];
    const float* a1 = (const float*)d_in[7];
    const float* W2 = (const float*)d_in[8];
    const float* a2 = (const float*)d_in[9];
    const float* rp = (const float*)d_in[10];
    const float* g  = (const float*)d_in[11];
    const float* be = (const float*)d_in[12];
    float* out = (float*)d_out;

    float* ws  = (float*)d_ws;
    float* W1s = ws;
    float* W2s = ws + 81920;
    float* qp  = ws + 163840;
    float* kp  = qp + BB * NH * LL * HD;
    float* vp  = kp + BB * NH * LL * HD;
    float* ctx = vp + BB * NH * LL * HD;
    unsigned short* Wt = (unsigned short*)ctx;  // aliases ctx (dead until k_attn)

    hipLaunchKernelGGL(k_pre, dim3(208), dim3(256), 0, stream,
                       a1, W1, a2, W2, Wq, Wk, Wv, W1s, W2s, Wt);
    hipLaunchKernelGGL(k_qkv, dim3(384), dim3(256), 0, stream, x, ts, Wt, qp, kp, vp);
    hipLaunchKernelGGL(k_attn, dim3(BB * NH * 32), dim3(256), 0, stream,
                       qp, kp, vp, ts, rp, am, W1s, W2s, ctx);
    hipLaunchKernelGGL(k_ln, dim3(BB * LL), dim3(256), 0, stream, ctx, x, g, be, out);
}

// Round 8
// 139.938 us; speedup vs baseline: 2.7925x; 1.1024x over previous
//
#include <hip/hip_runtime.h>
#include <math.h>

#define BB 4
#define LL 512
#define EMB 256
#define NH 8
#define HD 32
#define NB_ 3
#define CCN 10
#define NBKT 32
#define SCALE 0.17677669529663687f

typedef __bf16 bf16_t;
typedef __attribute__((ext_vector_type(8))) bf16_t bf16x8;
typedef __attribute__((ext_vector_type(4))) float f32x4;

__device__ __forceinline__ unsigned short f2b(float f) {
    unsigned int u = __float_as_uint(f);
    u += 0x7FFF + ((u >> 16) & 1);   // RNE
    return (unsigned short)(u >> 16);
}
__device__ __forceinline__ float b2f(unsigned short s) {
    return __uint_as_float(((unsigned int)s) << 16);
}
__device__ __forceinline__ unsigned pack2(float a, float b) {
    return (unsigned)f2b(a) | ((unsigned)f2b(b) << 16);
}
__device__ __forceinline__ int bm_of(int tq, int tk) {
    return (tq * tk != 0) ? ((tq - 1) * 3 + tk) : 0;
}
__device__ __forceinline__ unsigned long long shfl_up64(unsigned long long v, int d) {
    unsigned lo = (unsigned)__shfl_up((int)(unsigned)v, d, 64);
    unsigned hi = (unsigned)__shfl_up((int)(v >> 32), d, 64);
    return (((unsigned long long)hi) << 32) | lo;
}

// Stable counting sort of 512 tokens by type (4 types), 256 threads.
__device__ __forceinline__ void sort512(const int* __restrict__ tsb, int* spk,
                                        unsigned long long* wtll, int* msc, int tid) {
    int ty0 = tsb[2 * tid], ty1 = tsb[2 * tid + 1];
    unsigned long long pk = (1ULL << (16 * ty0)) + (1ULL << (16 * ty1));
    unsigned long long v = pk;
    int lane = tid & 63;
#pragma unroll
    for (int off = 1; off < 64; off <<= 1) {
        unsigned long long o = shfl_up64(v, off);
        if (lane >= off) v += o;
    }
    int w = tid >> 6;
    if (lane == 63) wtll[w] = v;
    __syncthreads();
    unsigned long long pre = 0, tot = 0;
#pragma unroll
    for (int i = 0; i < 4; i++) {
        unsigned long long xx = wtll[i];
        if (i < w) pre += xx;
        tot += xx;
    }
    v += pre;
    unsigned long long excl = v - pk;
    int c0 = (int)(tot & 0xFFFF), c1 = (int)((tot >> 16) & 0xFFFF);
    int c2 = (int)((tot >> 32) & 0xFFFF), c3 = (int)((tot >> 48) & 0xFFFF);
    int ub0 = 0, ub1 = c0, ub2 = c0 + c1, ub3 = c0 + c1 + c2;
    if (tid == 0) {
        int pc0 = (c0 + 31) & ~31, pc1 = (c1 + 31) & ~31, pc2 = (c2 + 31) & ~31, pc3 = (c3 + 31) & ~31;
        int pb1 = pc0, pb2 = pc0 + pc1, pb3 = pc0 + pc1 + pc2;
        msc[0] = 0;  msc[1] = pb1; msc[2] = pb2; msc[3] = pb3;
        msc[4] = ub0; msc[5] = ub1; msc[6] = ub2; msc[7] = ub3;
        msc[8] = c0; msc[9] = c1; msc[10] = c2; msc[11] = c3;
        msc[12] = (pb3 + pc3 + 63) & ~63;
    }
    int bases[4] = {ub0, ub1, ub2, ub3};
    int r0 = (int)((excl >> (16 * ty0)) & 0xFFFF);
    unsigned long long excl1 = excl + (1ULL << (16 * ty0));
    int r1 = (int)((excl1 >> (16 * ty1)) & 0xFFFF);
    spk[bases[ty0] + r0] = (ty0 << 16) | (2 * tid);
    spk[bases[ty1] + r1] = (ty1 << 16) | (2 * tid + 1);
    __syncthreads();
}

__device__ __forceinline__ void pad_lookup(const int* msc, int pos, int& real, int& upos, int& seg) {
    seg = (pos >= msc[1]) + (pos >= msc[2]) + (pos >= msc[3]);
    int r = pos - msc[seg];
    real = (r < msc[8 + seg]) ? 1 : 0;
    upos = msc[4 + seg] + r;
}

// ---------------- K0: weight combine (+ bf16 transposed copies) + QKV weight transpose ----------------
__global__ void k_pre(const float* __restrict__ A1, const float* __restrict__ W1,
                      const float* __restrict__ A2, const float* __restrict__ W2,
                      const float* __restrict__ Wq, const float* __restrict__ Wk, const float* __restrict__ Wv,
                      float* __restrict__ W1s, float* __restrict__ W2s,
                      unsigned short* __restrict__ W1Tb, unsigned short* __restrict__ W2Tb,
                      unsigned short* __restrict__ Wt) {
    __shared__ float cmb[32 * 33];            // combine tile
    __shared__ unsigned short ls[64 * 264];   // transpose tile
    int g = blockIdx.x, tid = threadIdx.x;
    if (g < 160) {
        int idx = g;
        const float* alpha = (idx < 80) ? A1 : A2;
        const float* W     = (idx < 80) ? W1 : W2;
        float* Ws          = (idx < 80) ? W1s : W2s;
        unsigned short* WT = (idx < 80) ? W1Tb : W2Tb;
        idx %= 80;
        int cc = idx / NH, h = idx % NH;
        float a0 = alpha[cc * NB_ * NH + 0 * NH + h];
        float a1 = alpha[cc * NB_ * NH + 1 * NH + h];
        float a2 = alpha[cc * NB_ * NH + 2 * NH + h];
        float mx = fmaxf(a0, fmaxf(a1, a2));
        float e0 = __expf(a0 - mx), e1 = __expf(a1 - mx), e2 = __expf(a2 - mx);
        float inv = 1.0f / (e0 + e1 + e2);
        e0 *= inv; e1 *= inv; e2 *= inv;
        for (int i = tid; i < HD * HD; i += 256) {
            int m = i >> 5, n = i & 31;
            float acc = e0 * W[((0 * NH + h) * HD + m) * HD + n]
                      + e1 * W[((1 * NH + h) * HD + m) * HD + n]
                      + e2 * W[((2 * NH + h) * HD + m) * HD + n];
            cmb[m * 33 + n] = acc;
        }
        __syncthreads();
        for (int i = tid; i < HD * HD; i += 256) {
            int a = i >> 5, bq = i & 31;
            Ws[((cc * NH + h) * HD + a) * HD + bq] = cmb[a * 33 + bq];
            // WT[a][bq] = cmb[bq][a]  (transposed bf16)
            WT[((size_t)(cc * NH + h) * HD + a) * HD + bq] = f2b(cmb[bq * 33 + a]);
        }
        return;
    }
    // transpose blocks: 48 = 12 tw x 4 out-blocks of 64
    int t = g - 160;
    int tw = t >> 2, ob = t & 3;
    int which = tw >> 2, ty = tw & 3;
    const float* src = ((which == 0) ? Wq : (which == 1) ? Wk : Wv) + (size_t)ty * EMB * EMB;
    int out0 = ob * 64;
    for (int it = 0; it < 16; it++) {
        int e = it * 16 + (tid >> 4);
        int o4 = (tid & 15) * 4;
        float4 v = *(const float4*)&src[(size_t)e * EMB + out0 + o4];
        ls[(o4 + 0) * 264 + e] = f2b(v.x);
        ls[(o4 + 1) * 264 + e] = f2b(v.y);
        ls[(o4 + 2) * 264 + e] = f2b(v.z);
        ls[(o4 + 3) * 264 + e] = f2b(v.w);
    }
    __syncthreads();
    int out = tid >> 2, ech = (tid & 3) * 8;
    unsigned short* dst = Wt + (size_t)tw * EMB * EMB + (size_t)(out0 + out) * EMB;
    const unsigned short* srcl = &ls[out * 264];
#pragma unroll
    for (int jj = 0; jj < 8; jj++)
        *(uint4*)&dst[ech + jj * 32] = *(const uint4*)&srcl[ech + jj * 32];
}

// ---------------- K1: QKV projection as segment-wise MFMA GEMM (unchanged) ----------------
__global__ __launch_bounds__(256, 4) void k_qkv(
    const float* __restrict__ x, const int* __restrict__ ts,
    const unsigned short* __restrict__ Wt,
    float* __restrict__ qp, float* __restrict__ kp, float* __restrict__ vp) {
    __shared__ int spk[LL];
    __shared__ unsigned long long wtll[4];
    __shared__ int msc[16];
    __shared__ unsigned short xs[32 * 264];
    __shared__ unsigned short wt[128 * 72];

    int g = blockIdx.x, tid = threadIdx.x;
    int ns = g % 6, gb = g / 6;
    int b = gb >> 4, tb = gb & 15, i0 = tb * 32;
    int which = ns >> 1, nh = ns & 1;
    int wave = tid >> 6, lane = tid & 63, quad = lane >> 4, col = lane & 15;

    sort512(ts + b * LL, spk, wtll, msc, tid);

    {
        int tok = tid >> 3, e32 = (tid & 7) * 32;
        int tok_orig = spk[i0 + tok] & 0xFFFF;
        const float* src = &x[(size_t)(b * LL + tok_orig) * EMB + e32];
        unsigned short* dstl = &xs[tok * 264 + e32];
#pragma unroll
        for (int jj = 0; jj < 4; jj++) {
            float4 v0 = *(const float4*)&src[jj * 8];
            float4 v1 = *(const float4*)&src[jj * 8 + 4];
            uint4 w;
            w.x = pack2(v0.x, v0.y); w.y = pack2(v0.z, v0.w);
            w.z = pack2(v1.x, v1.y); w.w = pack2(v1.z, v1.w);
            *(uint4*)&dstl[jj * 8] = w;
        }
    }
    int t_start = spk[i0] >> 16, t_end = spk[i0 + 31] >> 16;
    float* outp = (which == 0) ? qp : (which == 1) ? kp : vp;

    for (int ty = t_start; ty <= t_end; ty++) {
        f32x4 acc[2][2];
#pragma unroll
        for (int mt = 0; mt < 2; mt++)
#pragma unroll
            for (int nt = 0; nt < 2; nt++) acc[mt][nt] = (f32x4){0.f, 0.f, 0.f, 0.f};
        const unsigned short* wsrc = Wt + (size_t)(which * 4 + ty) * EMB * EMB + (size_t)(nh * 128) * EMB;
        for (int c = 0; c < 4; c++) {
            {
                int outloc = tid >> 1, e32 = (tid & 1) * 32;
                const unsigned short* srcw = &wsrc[(size_t)outloc * EMB + c * 64 + e32];
                unsigned short* dstw = &wt[outloc * 72 + e32];
#pragma unroll
                for (int jj = 0; jj < 4; jj++)
                    *(uint4*)&dstw[jj * 8] = *(const uint4*)&srcw[jj * 8];
            }
            __syncthreads();
#pragma unroll
            for (int kk = 0; kk < 2; kk++) {
                bf16x8 a0 = *(const bf16x8*)&xs[(0 * 16 + col) * 264 + c * 64 + kk * 32 + quad * 8];
                bf16x8 a1 = *(const bf16x8*)&xs[(1 * 16 + col) * 264 + c * 64 + kk * 32 + quad * 8];
                bf16x8 b0 = *(const bf16x8*)&wt[((wave * 2 + 0) * 16 + col) * 72 + kk * 32 + quad * 8];
                bf16x8 b1 = *(const bf16x8*)&wt[((wave * 2 + 1) * 16 + col) * 72 + kk * 32 + quad * 8];
                acc[0][0] = __builtin_amdgcn_mfma_f32_16x16x32_bf16(a0, b0, acc[0][0], 0, 0, 0);
                acc[0][1] = __builtin_amdgcn_mfma_f32_16x16x32_bf16(a0, b1, acc[0][1], 0, 0, 0);
                acc[1][0] = __builtin_amdgcn_mfma_f32_16x16x32_bf16(a1, b0, acc[1][0], 0, 0, 0);
                acc[1][1] = __builtin_amdgcn_mfma_f32_16x16x32_bf16(a1, b1, acc[1][1], 0, 0, 0);
            }
            __syncthreads();
        }
#pragma unroll
        for (int mt = 0; mt < 2; mt++)
#pragma unroll
            for (int r = 0; r < 4; r++) {
                int tokloc = mt * 16 + quad * 4 + r;
                int tty = spk[i0 + tokloc] >> 16;
                if (tty != ty) continue;
#pragma unroll
                for (int nt = 0; nt < 2; nt++) {
                    int n = nh * 128 + (wave * 2 + nt) * 16 + col;
                    int h = n >> 5, d = n & 31;
                    outp[((size_t)(b * NH + h) * LL + i0 + tokloc) * HD + d] = acc[mt][nt][r];
                }
            }
    }
}

// ---------------- K2: attention core, MFMA everywhere ----------------
#define SCP 648
#define OFF_UN   20736
#define OFF_QTB  29184
#define OFF_KPAD 33536
#define OFF_TBL  36096
#define OFF_RPL  37120
#define OFF_WT   38400
#define OFF_QOR  38432
#define OFF_QTY  38496
#define OFF_INV  38560
#define OFF_MSC  38624
#define SM_TOTAL 38688
__global__ __launch_bounds__(256, 4) void k_attn(
    const float* __restrict__ qp, const float* __restrict__ kp, const float* __restrict__ vp,
    const int* __restrict__ ts, const float* __restrict__ rp, const float* __restrict__ am,
    const float* __restrict__ W1s, const float* __restrict__ W2s,
    const unsigned short* __restrict__ W1Tb, const unsigned short* __restrict__ W2Tb,
    float* __restrict__ ctx) {
    __shared__ __align__(16) char smem[SM_TOTAL];
    unsigned short* scu = (unsigned short*)smem;
    int*   spk  = (int*)smem;
    unsigned short* qstb = (unsigned short*)(smem + OFF_UN);   // [16*40] bf16 q (prologue)
    unsigned short* kbuf = (unsigned short*)(smem + OFF_UN);   // [64*40] (pass1)
    unsigned short* vt   = (unsigned short*)(smem + OFF_UN);   // [32*72] (pass3)
    float* sb   = (float*)(smem + OFF_UN);                     // [16*132] fp32 buckets
    unsigned short* qtb = (unsigned short*)(smem + OFF_QTB);   // [16*136] bf16 qt  / later sbb
    unsigned short* sbb = (unsigned short*)(smem + OFF_QTB);   // alias (qtb dead after pass1)
    int*   kpad = (int*)(smem + OFF_KPAD);
    short* tbl  = (short*)(smem + OFF_TBL);
    float* rp_l = (float*)(smem + OFF_RPL);
    unsigned long long* wtll = (unsigned long long*)(smem + OFF_WT);
    int*   qor_l = (int*)(smem + OFF_QOR);
    int*   qty_l = (int*)(smem + OFF_QTY);
    float* inv_l = (float*)(smem + OFF_INV);
    int*   msc   = (int*)(smem + OFF_MSC);

    int blk = blockIdx.x;
    int b = blk >> 8, h = (blk >> 5) & 7, q16 = blk & 31;
    int i0q = q16 * 16;
    int tid = threadIdx.x;
    int wave = tid >> 6, lane = tid & 63, quad = lane >> 4, col = lane & 15;
    int bh = b * NH + h;

    for (int d = tid; d < LL; d += 256) {
        int v;
        if (d < 8) v = d;
        else {
            double r = log((double)d / 8.0) / log(5.0);
            v = 8 + (int)(r * 8.0);
            if (v > 15) v = 15;
        }
        tbl[d] = (short)v;
    }
    for (int i = tid; i < CCN * NBKT; i += 256) rp_l[i] = rp[i * NH + h];

    sort512(ts + b * LL, spk, wtll, msc, tid);

    int KT = msc[12];
    if (tid < 16) {
        int v = spk[i0q + tid];
        qor_l[tid] = v & 0xFFFF; qty_l[tid] = v >> 16;
    }
    for (int pos = tid; pos < KT; pos += 256) {
        int real, upos, seg;
        pad_lookup(msc, pos, real, upos, seg);
        kpad[pos] = real ? spk[upos] : ((seg << 16) | 0xFFFF);
    }
    {   // stage 16 q rows bf16 (pitch 40)
        int q = tid >> 4, m2 = (tid & 15) * 2;
        const float* src = &qp[((size_t)bh * LL + i0q + q) * HD + m2];
        ((unsigned*)qstb)[q * 20 + (tid & 15)] = pack2(src[0], src[1]);
    }
    __syncthreads();

    int qor_r[4], qty_r[4];
#pragma unroll
    for (int r = 0; r < 4; r++) { qor_r[r] = qor_l[quad * 4 + r]; qty_r[r] = qty_l[quad * 4 + r]; }
    bool uniq = (qty_l[0] == qty_l[15]);   // sorted -> uniform iff endpoints equal
    int tqu = qty_l[0];

    // ---- qt: qt[q][tk][n] = sum_m q[m] * W1_[bm(tq,tk)][h][m][n] ----
    if (uniq) {
#pragma unroll
        for (int it = 0; it < 2; it++) {
            int t8 = wave * 2 + it;            // 0..7 -> (tk, n-half)
            int tk = t8 >> 1, nhf = t8 & 1;
            int bmv = bm_of(tqu, tk);
            bf16x8 a = *(const bf16x8*)&qstb[col * 40 + quad * 8];
            bf16x8 bb = *(const bf16x8*)&W1Tb[((size_t)(bmv * NH + h) * HD + nhf * 16 + col) * HD + quad * 8];
            f32x4 d = {0.f, 0.f, 0.f, 0.f};
            d = __builtin_amdgcn_mfma_f32_16x16x32_bf16(a, bb, d, 0, 0, 0);
#pragma unroll
            for (int r = 0; r < 4; r++)
                qtb[(quad * 4 + r) * 136 + tk * 32 + nhf * 16 + col] = f2b(d[r]);
        }
    } else {
        for (int i = tid; i < 16 * 128; i += 256) {
            int q = i >> 7, r = i & 127, tk = r >> 5, n = r & 31;
            int bmv = bm_of(qty_l[q], tk);
            const float* wb = &W1s[((bmv * NH + h) * HD) * HD + n];
            float acc = 0.f;
#pragma unroll
            for (int m = 0; m < HD; m++) acc += b2f(qstb[q * 40 + m]) * wb[m * HD];
            qtb[q * 136 + tk * 32 + n] = f2b(acc);
        }
    }
    __syncthreads();

    // ---- pass 1: scores via MFMA, in-loop bias/mask epilogue ----
    const float* amb = am + (size_t)b * LL * LL;
    for (int kt0 = 0; kt0 < KT; kt0 += 64) {
        {
            int kk = tid >> 2, m8 = (tid & 3) * 8;
            int real, upos, seg;
            pad_lookup(msc, kt0 + kk, real, upos, seg);
            uint4 w = make_uint4(0, 0, 0, 0);
            if (real) {
                const float4* src = (const float4*)&kp[((size_t)bh * LL + upos) * HD + m8];
                float4 v0 = src[0], v1 = src[1];
                w.x = pack2(v0.x, v0.y); w.y = pack2(v0.z, v0.w);
                w.z = pack2(v1.x, v1.y); w.w = pack2(v1.z, v1.w);
            }
            *(uint4*)&kbuf[kk * 40 + m8] = w;
        }
        __syncthreads();
        {
            int kb = kt0 + wave * 16;
            int tk = kpad[kb] >> 16;
            bf16x8 a = *(const bf16x8*)&qtb[col * 136 + tk * 32 + quad * 8];
            bf16x8 bfr = *(const bf16x8*)&kbuf[(wave * 16 + col) * 40 + quad * 8];
            f32x4 d = {0.f, 0.f, 0.f, 0.f};
            d = __builtin_amdgcn_mfma_f32_16x16x32_bf16(a, bfr, d, 0, 0, 0);
            int kpi = kb + col;
            int kv = kpad[kpi];
            int ko = kv & 0xFFFF;
            if (ko == 0xFFFF) {
#pragma unroll
                for (int r = 0; r < 4; r++) scu[(quad * 4 + r) * SCP + kpi] = 0xFF80;
            } else {
                int tkk = kv >> 16;
#pragma unroll
                for (int r = 0; r < 4; r++) {
                    int q = quad * 4 + r;
                    int qo = qor_r[r];
                    int dd = qo - ko;
                    int ad = dd < 0 ? -dd : dd;
                    int bk = (dd < 0 ? 16 : 0) + (int)tbl[ad];
                    float bias = rp_l[bm_of(qty_r[r], tkk) * NBKT + bk];
                    float mval = amb[(size_t)qo * LL + ko];
                    scu[q * SCP + kpi] = f2b(d[r] * SCALE + bias + mval);
                }
            }
        }
        __syncthreads();
    }

    // ---- pass 2: softmax ----
    {
        int gq = tid >> 4, t16 = tid & 15;
        float mx = -1e30f;
        for (int kk = t16; kk < KT; kk += 16) mx = fmaxf(mx, b2f(scu[gq * SCP + kk]));
#pragma unroll
        for (int off = 1; off < 16; off <<= 1) mx = fmaxf(mx, __shfl_xor(mx, off, 16));
        float sum = 0.f;
        for (int kk = t16; kk < KT; kk += 16) {
            int idx = gq * SCP + kk;
            float e = __expf(b2f(scu[idx]) - mx);
            scu[idx] = f2b(e); sum += e;
        }
#pragma unroll
        for (int off = 1; off < 16; off <<= 1) sum += __shfl_xor(sum, off, 16);
        if (t16 == 0) inv_l[gq] = 1.0f / sum;
    }
    __syncthreads();

    // ---- pass 3: PV via MFMA (vt rows permuted) ----
    f32x4 accv[4][2];
#pragma unroll
    for (int t = 0; t < 4; t++)
#pragma unroll
        for (int hh = 0; hh < 2; hh++) accv[t][hh] = (f32x4){0.f, 0.f, 0.f, 0.f};

    for (int kt0 = 0; kt0 < KT; kt0 += 64) {
        {
            int kk = tid >> 2, n8 = (tid & 3) * 8;
            int real, upos, seg;
            pad_lookup(msc, kt0 + kk, real, upos, seg);
            float vv[8] = {0, 0, 0, 0, 0, 0, 0, 0};
            if (real) {
                const float4* src = (const float4*)&vp[((size_t)bh * LL + upos) * HD + n8];
                float4 v0 = src[0], v1 = src[1];
                vv[0] = v0.x; vv[1] = v0.y; vv[2] = v0.z; vv[3] = v0.w;
                vv[4] = v1.x; vv[5] = v1.y; vv[6] = v1.z; vv[7] = v1.w;
            }
#pragma unroll
            for (int i = 0; i < 8; i++) {
                int n = n8 + i;
                int ph = ((n & 3) << 3) | (n >> 2);
                vt[ph * 72 + kk] = f2b(vv[i]);
            }
        }
        __syncthreads();
        int c = kt0 >> 6;
        int g0 = 2 * c;
        int pc = ((col & 3) << 3) | (col >> 2);
#pragma unroll
        for (int gl = 0; gl < 2; gl++) {
            int g = g0 + gl;
            if ((g & 3) != wave) continue;
            int loc = gl * 32;
            int tk = kpad[kt0 + loc] >> 16;
            bf16x8 a = *(const bf16x8*)&scu[col * SCP + kt0 + loc + quad * 8];
            bf16x8 b0 = *(const bf16x8*)&vt[pc * 72 + loc + quad * 8];
            bf16x8 b1 = *(const bf16x8*)&vt[(pc + 4) * 72 + loc + quad * 8];
            if (tk == 0) {
                accv[0][0] = __builtin_amdgcn_mfma_f32_16x16x32_bf16(a, b0, accv[0][0], 0, 0, 0);
                accv[0][1] = __builtin_amdgcn_mfma_f32_16x16x32_bf16(a, b1, accv[0][1], 0, 0, 0);
            } else if (tk == 1) {
                accv[1][0] = __builtin_amdgcn_mfma_f32_16x16x32_bf16(a, b0, accv[1][0], 0, 0, 0);
                accv[1][1] = __builtin_amdgcn_mfma_f32_16x16x32_bf16(a, b1, accv[1][1], 0, 0, 0);
            } else if (tk == 2) {
                accv[2][0] = __builtin_amdgcn_mfma_f32_16x16x32_bf16(a, b0, accv[2][0], 0, 0, 0);
                accv[2][1] = __builtin_amdgcn_mfma_f32_16x16x32_bf16(a, b1, accv[2][1], 0, 0, 0);
            } else {
                accv[3][0] = __builtin_amdgcn_mfma_f32_16x16x32_bf16(a, b0, accv[3][0], 0, 0, 0);
                accv[3][1] = __builtin_amdgcn_mfma_f32_16x16x32_bf16(a, b1, accv[3][1], 0, 0, 0);
            }
        }
        __syncthreads();
    }

    // ---- cross-wave reduction; last wave also emits bf16 sbb (A-frag layout) ----
#pragma unroll
    for (int w = 0; w < 4; w++) {
        if (wave == w) {
#pragma unroll
            for (int t = 0; t < 4; t++)
#pragma unroll
                for (int hh = 0; hh < 2; hh++)
#pragma unroll
                    for (int r = 0; r < 4; r++) {
                        int q = quad * 4 + r;
                        int n = col + 16 * hh;
                        float val = accv[t][hh][r];
                        if (w == 0) {
                            sb[q * 132 + t * 32 + n] = val;
                        } else if (w < 3) {
                            sb[q * 132 + t * 32 + n] += val;
                        } else {
                            float fin = sb[q * 132 + t * 32 + n] + val;
                            sb[q * 132 + t * 32 + n] = fin;
                            sbb[q * 136 + t * 32 + n] = f2b(fin);
                        }
                    }
        }
        __syncthreads();
    }

    // ---- ctx epilogue ----
    if (uniq) {
        if (wave < 2) {
            int mhf = wave;
            f32x4 d = {0.f, 0.f, 0.f, 0.f};
#pragma unroll
            for (int tk = 0; tk < 4; tk++) {
                int bmv = bm_of(tqu, tk);
                bf16x8 a = *(const bf16x8*)&sbb[col * 136 + tk * 32 + quad * 8];
                bf16x8 bb = *(const bf16x8*)&W2Tb[((size_t)(bmv * NH + h) * HD + mhf * 16 + col) * HD + quad * 8];
                d = __builtin_amdgcn_mfma_f32_16x16x32_bf16(a, bb, d, 0, 0, 0);
            }
#pragma unroll
            for (int r = 0; r < 4; r++) {
                int q = quad * 4 + r;
                ctx[((size_t)(b * LL + qor_l[q])) * EMB + h * HD + mhf * 16 + col] = d[r] * inv_l[q];
            }
        }
    } else {
        int m = tid & 31, qq = tid >> 5;
#pragma unroll
        for (int rep = 0; rep < 2; rep++) {
            int qi = qq + 8 * rep;
            int tq = qty_l[qi];
            float acc = 0.f;
#pragma unroll
            for (int tk2 = 0; tk2 < 4; tk2++) {
                int bmv = bm_of(tq, tk2);
                const float* wb = &W2s[((bmv * NH + h) * HD) * HD + m];
                const float* sbp = &sb[qi * 132 + tk2 * 32];
                for (int n = 0; n < HD; n++) acc += sbp[n] * wb[n * HD];
            }
            int qo = qor_l[qi];
            ctx[((size_t)(b * LL + qo)) * EMB + h * HD + m] = acc * inv_l[qi];
        }
    }
}

// ---------------- K3: residual + LayerNorm ----------------
__global__ void k_ln(const float* __restrict__ ctx, const float* __restrict__ x,
                     const float* __restrict__ gamma, const float* __restrict__ beta,
                     float* __restrict__ out) {
    __shared__ float red[8];
    __shared__ float red2[8];
    int blk = blockIdx.x;
    int b = blk >> 9, l = blk & 511;
    int j = threadIdx.x;
    size_t base = ((size_t)(b * LL + l)) * EMB;
    float v = ctx[base + j] + x[base + j];
    float s = v, s2 = v * v;
    for (int off = 32; off > 0; off >>= 1) { s += __shfl_down(s, off, 64); s2 += __shfl_down(s2, off, 64); }
    int wid = j >> 6;
    if ((j & 63) == 0) { red[wid] = s; red2[wid] = s2; }
    __syncthreads();
    if (j == 0) {
        float ts_ = 0, ts2 = 0;
        for (int w = 0; w < 4; w++) { ts_ += red[w]; ts2 += red2[w]; }
        red[4] = ts_; red2[4] = ts2;
    }
    __syncthreads();
    float mu = red[4] / (float)EMB;
    float var = red2[4] / (float)EMB - mu * mu;
    float r = rsqrtf(var + 1e-12f);
    out[base + j] = (v - mu) * r * gamma[j] + beta[j];
}

extern "C" void kernel_launch(void* const* d_in, const int* in_sizes, int n_in,
                              void* d_out, int out_size, void* d_ws, size_t ws_size,
                              hipStream_t stream) {
    const float* x  = (const float*)d_in[0];
    const float* am = (const float*)d_in[1];
    const int*   ts = (const int*)d_in[2];
    const float* Wq = (const float*)d_in[3];
    const float* Wk = (const float*)d_in[4];
    const float* Wv = (const float*)d_in[5];
    const float* W1 = (const float*)d_in[6];
    const float* a1 = (const float*)d_in[7];
    const float* W2 = (const float*)d_in[8];
    const float* a2 = (const float*)d_in[9];
    const float* rp = (const float*)d_in[10];
    const float* g  = (const float*)d_in[11];
    const float* be = (const float*)d_in[12];
    float* out = (float*)d_out;

    float* ws  = (float*)d_ws;
    float* W1s = ws;                                  // 81920 f
    float* W2s = ws + 81920;                          // 81920 f
    unsigned short* W1Tb = (unsigned short*)(ws + 163840);  // 81920 us (40960 f)
    unsigned short* W2Tb = (unsigned short*)(ws + 204800);  // 81920 us (40960 f)
    float* qp  = ws + 245760;                         // 524288 f each
    float* kp  = qp + BB * NH * LL * HD;
    float* vp  = kp + BB * NH * LL * HD;
    float* ctx = vp + BB * NH * LL * HD;
    unsigned short* Wt = (unsigned short*)ctx;        // aliases ctx (dead until k_attn)

    hipLaunchKernelGGL(k_pre, dim3(208), dim3(256), 0, stream,
                       a1, W1, a2, W2, Wq, Wk, Wv, W1s, W2s, W1Tb, W2Tb, Wt);
    hipLaunchKernelGGL(k_qkv, dim3(384), dim3(256), 0, stream, x, ts, Wt, qp, kp, vp);
    hipLaunchKernelGGL(k_attn, dim3(BB * NH * 32), dim3(256), 0, stream,
                       qp, kp, vp, ts, rp, am, W1s, W2s, W1Tb, W2Tb, ctx);
    hipLaunchKernelGGL(k_ln, dim3(BB * LL), dim3(256), 0, stream, ctx, x, g, be, out);
}